// Round 19
// baseline (99.243 us; speedup 1.0000x reference)
//
#include <hip/hip_runtime.h>
#include <hip/hip_bf16.h>
#include <math.h>

#define BATCH 4
#define CIN   256
#define DQK   32
#define NPIX  4096
#define MTOT  320

typedef __attribute__((ext_vector_type(4))) float f32x4;
typedef __attribute__((ext_vector_type(8))) short bf16x8;
typedef __attribute__((ext_vector_type(4))) unsigned int u32x4;

__device__ __forceinline__ unsigned short f2bf(float f) {
  unsigned u = __builtin_bit_cast(unsigned, f);
  u += 0x7FFFu + ((u >> 16) & 1u);   // RNE
  return (unsigned short)(u >> 16);
}
__device__ __forceinline__ unsigned pk2(float a, float b) {
  return (unsigned)f2bf(a) | ((unsigned)f2bf(b) << 16);
}
__device__ __forceinline__ void barrier_lds() {
  asm volatile("s_waitcnt lgkmcnt(0)" ::: "memory");
  __builtin_amdgcn_s_barrier();
  asm volatile("" ::: "memory");
}
__device__ __forceinline__ void wait_vm2_lgkm0() { asm volatile("s_waitcnt vmcnt(2) lgkmcnt(0)" ::: "memory"); }
__device__ __forceinline__ void wait_vm0_lgkm0() { asm volatile("s_waitcnt vmcnt(0) lgkmcnt(0)" ::: "memory"); }

#define GLD16(GP, LP) \
  __builtin_amdgcn_global_load_lds((const __attribute__((address_space(1))) void*)(GP), \
                                   (__attribute__((address_space(3))) void*)(LP), 16, 0, 0)

// ---------------- W convert ----------------
__global__ void wcvt(const float* __restrict__ Wh, const float* __restrict__ Wf,
                     const float* __restrict__ Wg,
                     const float* __restrict__ bh, const float* __restrict__ bf,
                     const float* __restrict__ bg,
                     unsigned short* __restrict__ Wb, float* __restrict__ bcat) {
  const int r = blockIdx.x;
  const int c = threadIdx.x;
  const float* src = (r < 256) ? &Wh[r * CIN] : (r < 288) ? &Wf[(r - 256) * CIN] : &Wg[(r - 288) * CIN];
  Wb[r * CIN + c] = f2bf(src[c]);
  if (c == 0)
    bcat[r] = (r < 256) ? bh[r] : (r < 288) ? bf[r - 256] : bg[r - 288];
}

// ---------------- fused projection GEMM (r2-proven) ----------------
#define XPAD 4
__launch_bounds__(512, 1)
__global__ void proj_all(const float* __restrict__ x, const unsigned short* __restrict__ Wb,
                         const float* __restrict__ bcat,
                         unsigned short* __restrict__ F, unsigned short* __restrict__ G,
                         unsigned short* __restrict__ H) {
  __shared__ unsigned short Xs[64 * (CIN + XPAD)];

  const int bid = blockIdx.x;
  const int b = bid >> 6;
  const int n0 = (bid & 63) << 6;
  const int t = threadIdx.x;
  const int lane = t & 63;
  const int w = t >> 6;

  const float* __restrict__ xb = x + (size_t)b * CIN * NPIX + n0;
#pragma unroll
  for (int p = 0; p < 16; ++p) {
    const int k = p * 16 + w * 2;
    const float a0 = xb[(size_t)k * NPIX + lane];
    const float a1 = xb[(size_t)(k + 1) * NPIX + lane];
    const unsigned pk = (unsigned)f2bf(a0) | ((unsigned)f2bf(a1) << 16);
    *(unsigned*)((char*)Xs + lane * (CIN + XPAD) * 2 + k * 2) = pk;
  }
  __syncthreads();

  const int l16 = lane & 15, lhi = lane >> 4;
  const int wm = w >> 1;
  const int wn = w & 1;

  const f32x4 fzero = {0.f, 0.f, 0.f, 0.f};
  f32x4 acc[5][2];
#pragma unroll
  for (int i = 0; i < 5; ++i)
#pragma unroll
    for (int j = 0; j < 2; ++j) acc[i][j] = fzero;

#pragma unroll
  for (int ks = 0; ks < 8; ++ks) {
    bf16x8 bx[2];
#pragma unroll
    for (int j = 0; j < 2; ++j)
      bx[j] = *(const bf16x8*)&Xs[(wn * 32 + j * 16 + l16) * (CIN + XPAD) + ks * 32 + lhi * 8];
#pragma unroll
    for (int i = 0; i < 5; ++i) {
      const bf16x8 aw = *(const bf16x8*)(Wb + (size_t)(wm * 80 + i * 16 + l16) * CIN + ks * 32 + lhi * 8);
#pragma unroll
      for (int j = 0; j < 2; ++j)
        acc[i][j] = __builtin_amdgcn_mfma_f32_16x16x32_bf16(aw, bx[j], acc[i][j], 0, 0, 0);
    }
  }

#pragma unroll
  for (int i = 0; i < 5; ++i) {
    const int MT = wm * 5 + i;
    const int m0 = MT * 16;
    const f32x4 bias = *(const f32x4*)&bcat[m0 + lhi * 4];
#pragma unroll
    for (int j = 0; j < 2; ++j) {
      const int n = n0 + wn * 32 + j * 16 + l16;
      f32x4 v = acc[i][j];
      v.x += bias.x; v.y += bias.y; v.z += bias.z; v.w += bias.w;
      if (MT < 16) {
        const int c0 = m0 + lhi * 4;
        unsigned short* dst = H + ((size_t)b * CIN + c0) * NPIX + n;
        dst[0 * NPIX] = f2bf(v.x);
        dst[1 * NPIX] = f2bf(v.y);
        dst[2 * NPIX] = f2bf(v.z);
        dst[3 * NPIX] = f2bf(v.w);
      } else {
        unsigned short* dst = (MT < 18) ? F : G;
        const int d0 = ((MT - 16) & 1) * 16 + lhi * 4;
        uint2 pk;
        pk.x = (unsigned)f2bf(v.x) | ((unsigned)f2bf(v.y) << 16);
        pk.y = (unsigned)f2bf(v.z) | ((unsigned)f2bf(v.w) << 16);
        *(uint2*)(dst + ((size_t)b * NPIX + n) * DQK + d0) = pk;
      }
    }
  }
}

// ---------------- fused flash attention v19: split=1, direct f32 out ----------------
// grid 256 (4b x 64qt; bid&3=b -> XCD slab grouping) x 16 waves (1024 thr). QT=64.
// Wave (mg 0..3: 16 queries, cs 0..3): QK = 1 MFMA (16q x 16k slice, zero dup);
// PV = 64ch(cs) x 16q(mg) over 64 keys (8 MFMA). Each block sees ALL 4096 keys
// (NTILE=64) -> full L in-block -> normalize + write f32 out directly.
// No Apart/Lpart/combine (saves 33.6MB HBM round-trip + 2 launches).
// K/V triple-buffered via global_load_lds (K first, waves 12-15); ONE
// {vmcnt(2)+lgkm0; barrier} per tile (r17-proven ledger). P parity-buffered.
#define BNK  64
#define NTILE (NPIX / BNK)   // 64

__launch_bounds__(1024, 1)
__global__ void attn_full(const unsigned short* __restrict__ F,
                          const unsigned short* __restrict__ G,
                          const unsigned short* __restrict__ H,
                          float* __restrict__ out) {
  __shared__ unsigned short Kl[3][64][32];       // [buf][n][32d]  linear 12 KB
  __shared__ unsigned short Vl[3][256][64];      // [buf][c][64n]  linear 96 KB
  __shared__ unsigned short Pl[2][4][16][72];    // [parity][mg][q][64n+pad] 18.4 KB
  __shared__ float Lred[4][4][16];               // [mg][cs][q] 1 KB

  const int bid = blockIdx.x;
  const int b = bid & 3;                         // slab grouping for XCD L2
  const int qt = bid >> 2;                       // 0..63
  const int t = threadIdx.x;
  const int lane = t & 63, w = t >> 6;           // w 0..15
  const int l16 = lane & 15, lhi = lane >> 4;
  const int mg = w >> 2, cs = w & 3;

  const unsigned short* Fb = F + (size_t)b * NPIX * DQK;
  const unsigned short* Gb = G + (size_t)b * NPIX * DQK;
  const unsigned short* Hb = H + (size_t)b * CIN * NPIX;
  const int q0 = qt * 64 + mg * 16;              // wave's 16-query base

  const f32x4 fzero = {0.f, 0.f, 0.f, 0.f};

  // Q fragment (B-operand): col m = l16, k = lhi*8..+7
  const bf16x8 qf = *(const bf16x8*)(Gb + (size_t)(q0 + l16) * DQK + lhi * 8);

  f32x4 acc[4];
#pragma unroll
  for (int ct = 0; ct < 4; ++ct) acc[ct] = fzero;
  float Lacc = 0.f;

  // async staging (pre-swizzled; involutions identical to r17):
  // V: wave w stages rows 8w+(lane>>3), 2 chunks (+128); slot (lane&7)^(lane>>3)
  const char* vsrc = (const char*)Hb + ((size_t)(8 * w + (lane >> 3)) * NPIX) * 2
                   + (((lane & 7) ^ (lane >> 3)) * 16);
  // K: waves 12..15 stage rows 16(w-12)+(lane>>2); slot (lane&3)^((lane>>2)&3)
  const int kw = (w >= 12) ? (w - 12) : 0;
  const char* ksrc = (const char*)Fb + ((size_t)(16 * kw + (lane >> 2)) * DQK) * 2
                   + (((lane & 3) ^ ((lane >> 2) & 3)) * 16);

// K issued FIRST so vmcnt(2) (keeping the 2 newer V loads) retires it on schedule
#define ISSUE(TT) do {                                                           \
    const int bu_ = (TT) % 3;                                                    \
    if (w >= 12)                                                                 \
      GLD16(ksrc + (size_t)(TT) * 64 * DQK * 2, &Kl[bu_][16 * kw][0]);           \
    _Pragma("unroll")                                                            \
    for (int i_ = 0; i_ < 2; ++i_)                                               \
      GLD16(vsrc + (size_t)i_ * 128 * NPIX * 2 + (size_t)(TT) * 128,             \
            &Vl[bu_][i_ * 128 + 8 * w][0]);                                      \
  } while (0)

  // QK (1 MFMA: keys cs*16+lhi*4+v, queries q0+l16) + exp -> Pl[PAR][mg]
#define QKSM(BUF3, PAR) do {                                                     \
    const unsigned short* kb_ = &Kl[BUF3][0][0];                                 \
    const bf16x8 kf_ = *(const bf16x8*)(kb_ + (cs * 16 + l16) * 32 + ((lhi ^ (l16 & 3)) * 8)); \
    const f32x4 s_ = __builtin_amdgcn_mfma_f32_16x16x32_bf16(kf_, qf, fzero, 0, 0, 0); \
    const float p0 = __expf(s_[0]), p1 = __expf(s_[1]);                          \
    const float p2 = __expf(s_[2]), p3 = __expf(s_[3]);                          \
    Lacc += (p0 + p1) + (p2 + p3);                                               \
    uint2 pk_; pk_.x = pk2(p0, p1); pk_.y = pk2(p2, p3);                         \
    *(uint2*)&Pl[PAR][mg][l16][cs * 16 + lhi * 4] = pk_;                         \
  } while (0)

  // PV: O^T(64ch x 16q) += V^T * P over 64 keys (8 MFMA)
#define PVACC(BUF3, PAR) do {                                                    \
    const unsigned short* vb_ = &Vl[BUF3][0][0];                                 \
    bf16x8 pf_[2];                                                               \
    _Pragma("unroll")                                                            \
    for (int kk_ = 0; kk_ < 2; ++kk_)                                            \
      pf_[kk_] = *(const bf16x8*)&Pl[PAR][mg][l16][kk_ * 32 + lhi * 8];          \
    __builtin_amdgcn_s_setprio(1);                                               \
    _Pragma("unroll")                                                            \
    for (int kk_ = 0; kk_ < 2; ++kk_)                                            \
      _Pragma("unroll")                                                          \
      for (int ct_ = 0; ct_ < 4; ++ct_) {                                        \
        const bf16x8 vf_ = *(const bf16x8*)(vb_ + (cs * 64 + ct_ * 16 + l16) * 64 \
                            + (((4 * kk_ + lhi) ^ (l16 & 7)) * 8));              \
        acc[ct_] = __builtin_amdgcn_mfma_f32_16x16x32_bf16(vf_, pf_[kk_], acc[ct_], 0, 0, 0); \
      }                                                                          \
    __builtin_amdgcn_s_setprio(0);                                               \
  } while (0)

  // prologue: tiles 0,1 in flight; vmcnt(2) retires {K0,V0,K1}, keeps V1x2
  ISSUE(0); ISSUE(1);
  wait_vm2_lgkm0();
  __builtin_amdgcn_s_barrier();
  asm volatile("" ::: "memory");
  QKSM(0, 0);

  for (int tt = 0; tt < NTILE; ++tt) {
    const int par = tt & 1;
    // the ONLY barrier per tile
    if (tt == NTILE - 1) wait_vm0_lgkm0(); else wait_vm2_lgkm0();
    __builtin_amdgcn_s_barrier();
    asm volatile("" ::: "memory");
    // buffer (tt+2)%3 was last read at iter tt-1 -> free now
    if (tt + 2 < NTILE) ISSUE(tt + 2);
    if (tt + 1 < NTILE) QKSM((tt + 1) % 3, par ^ 1);
    PVACC(tt % 3, par);
  }
#undef ISSUE
#undef QKSM
#undef PVACC

  // epilogue: cross-cs L reduction in LDS, then normalized f32 stores
  {
    float L = Lacc;
    L += __shfl_xor(L, 16, 64);
    L += __shfl_xor(L, 32, 64);
    if (lhi == 0) Lred[mg][cs][l16] = L;
  }
  barrier_lds();
  const float invL = 1.f / (Lred[mg][0][l16] + Lred[mg][1][l16] +
                            Lred[mg][2][l16] + Lred[mg][3][l16]);
  const int q = q0 + l16;
#pragma unroll
  for (int ct = 0; ct < 4; ++ct) {
    const int c = cs * 64 + ct * 16 + lhi * 4;
    float* dst = out + ((size_t)b * CIN + c) * NPIX + q;
#pragma unroll
    for (int v = 0; v < 4; ++v) dst[(size_t)v * NPIX] = acc[ct][v] * invL;
  }
}

// ---------------- fallback flash attention (r2-proven; ws too small) ----------------
#define BN 32
__launch_bounds__(512, 2)
__global__ void attn_kernel(const unsigned short* __restrict__ F,
                            const unsigned short* __restrict__ G,
                            const unsigned short* __restrict__ H,
                            float* __restrict__ out) {
  __shared__ unsigned short Klds[32 * 40];
  __shared__ unsigned short Vlds[256 * 40];
  __shared__ unsigned short Plds[8][32 * 40];

  const int bid = blockIdx.x;
  const int b = bid >> 6;
  const int t = threadIdx.x;
  const int lane = t & 63;
  const int w = t >> 6;
  const int l16 = lane & 15;
  const int lhi = lane >> 4;
  const int m0 = ((bid & 63) << 6) + ((w >> 2) << 5);
  const int c0 = (w & 3) << 6;

  const f32x4 fzero = {0.f, 0.f, 0.f, 0.f};

  bf16x8 qf[2];
#pragma unroll
  for (int mt = 0; mt < 2; ++mt)
    qf[mt] = *(const bf16x8*)(G + ((size_t)b * NPIX + m0 + mt * 16 + l16) * DQK + lhi * 8);

  f32x4 acc[4][2];
#pragma unroll
  for (int ct = 0; ct < 4; ++ct)
#pragma unroll
    for (int mt = 0; mt < 2; ++mt) acc[ct][mt] = fzero;
  float Mr[2] = {-INFINITY, -INFINITY};
  float Lr[2] = {0.f, 0.f};

  const unsigned short* Fb = F + (size_t)b * NPIX * DQK;
  const unsigned short* Hb = H + (size_t)b * CIN * NPIX;
  unsigned short* Pw = &Plds[w][0];

  for (int n0 = 0; n0 < NPIX; n0 += BN) {
    __syncthreads();
    if (t < 128) {
      const int nr = t >> 2, sl = t & 3;
      *(u32x4*)&Klds[nr * 40 + sl * 8] = *(const u32x4*)(Fb + (size_t)(n0 + nr) * DQK + sl * 8);
    }
#pragma unroll
    for (int i = 0; i < 2; ++i) {
      const int q = t + i * 512;
      const int cr = q >> 2, sl = q & 3;
      *(u32x4*)&Vlds[cr * 40 + sl * 8] = *(const u32x4*)(Hb + (size_t)cr * NPIX + n0 + sl * 8);
    }
    __syncthreads();

    bf16x8 kf[2];
#pragma unroll
    for (int nts = 0; nts < 2; ++nts)
      kf[nts] = *(const bf16x8*)&Klds[(nts * 16 + l16) * 40 + lhi * 8];
    f32x4 s[2][2];
#pragma unroll
    for (int mt = 0; mt < 2; ++mt)
#pragma unroll
      for (int nts = 0; nts < 2; ++nts)
        s[mt][nts] = __builtin_amdgcn_mfma_f32_16x16x32_bf16(kf[nts], qf[mt], fzero, 0, 0, 0);

#pragma unroll
    for (int mt = 0; mt < 2; ++mt) {
      float tmax = s[mt][0][0];
#pragma unroll
      for (int v = 1; v < 4; ++v) tmax = fmaxf(tmax, s[mt][0][v]);
#pragma unroll
      for (int v = 0; v < 4; ++v) tmax = fmaxf(tmax, s[mt][1][v]);
      tmax = fmaxf(tmax, __shfl_xor(tmax, 16, 64));
      tmax = fmaxf(tmax, __shfl_xor(tmax, 32, 64));
      const float newM = fmaxf(Mr[mt], tmax);
      const float rescale = __expf(Mr[mt] - newM);
      Mr[mt] = newM;
      float p[2][4];
      float psum = 0.f;
#pragma unroll
      for (int nts = 0; nts < 2; ++nts)
#pragma unroll
        for (int v = 0; v < 4; ++v) {
          p[nts][v] = __expf(s[mt][nts][v] - newM);
          psum += p[nts][v];
        }
      psum += __shfl_xor(psum, 16, 64);
      psum += __shfl_xor(psum, 32, 64);
      Lr[mt] = Lr[mt] * rescale + psum;
#pragma unroll
      for (int ct = 0; ct < 4; ++ct) acc[ct][mt] *= rescale;
#pragma unroll
      for (int nts = 0; nts < 2; ++nts) {
        uint2 pkv;
        pkv.x = (unsigned)f2bf(p[nts][0]) | ((unsigned)f2bf(p[nts][1]) << 16);
        pkv.y = (unsigned)f2bf(p[nts][2]) | ((unsigned)f2bf(p[nts][3]) << 16);
        *(uint2*)&Pw[(mt * 16 + l16) * 40 + nts * 16 + lhi * 4] = pkv;
      }
    }
    asm volatile("" ::: "memory");

    bf16x8 pf[2];
#pragma unroll
    for (int mt = 0; mt < 2; ++mt)
      pf[mt] = *(const bf16x8*)&Pw[(mt * 16 + l16) * 40 + lhi * 8];
#pragma unroll
    for (int ct = 0; ct < 4; ++ct) {
      const bf16x8 vf = *(const bf16x8*)&Vlds[(c0 + ct * 16 + l16) * 40 + lhi * 8];
#pragma unroll
      for (int mt = 0; mt < 2; ++mt)
        acc[ct][mt] = __builtin_amdgcn_mfma_f32_16x16x32_bf16(vf, pf[mt], acc[ct][mt], 0, 0, 0);
    }
  }

#pragma unroll
  for (int mt = 0; mt < 2; ++mt) {
    const float invL = 1.f / Lr[mt];
    const int m = m0 + mt * 16 + l16;
#pragma unroll
    for (int ct = 0; ct < 4; ++ct)
#pragma unroll
      for (int v = 0; v < 4; ++v) {
        const int c = c0 + ct * 16 + lhi * 4 + v;
        out[((size_t)b * CIN + c) * NPIX + m] = acc[ct][mt][v] * invL;
      }
  }
}

extern "C" void kernel_launch(void* const* d_in, const int* in_sizes, int n_in,
                              void* d_out, int out_size, void* d_ws, size_t ws_size,
                              hipStream_t stream) {
  (void)in_sizes; (void)n_in; (void)out_size;
  const float* x  = (const float*)d_in[0];
  const float* Wf = (const float*)d_in[1];
  const float* bf = (const float*)d_in[2];
  const float* Wg = (const float*)d_in[3];
  const float* bg = (const float*)d_in[4];
  const float* Wh = (const float*)d_in[5];
  const float* bh = (const float*)d_in[6];
  float* out = (float*)d_out;

  // workspace: F 1MB | G 1MB | H 8.4MB | Wb 160KB | bcat 1.25KB (~10.7MB)
  unsigned short* Fw = (unsigned short*)d_ws;
  unsigned short* Gw = Fw + (size_t)BATCH * NPIX * DQK;
  unsigned short* Hw = Gw + (size_t)BATCH * NPIX * DQK;
  unsigned short* Wb = Hw + (size_t)BATCH * CIN * NPIX;
  float* bcat = (float*)(Wb + (size_t)MTOT * CIN);
  const size_t NEED = (size_t)((char*)(bcat + MTOT) - (char*)d_ws);

  hipLaunchKernelGGL(wcvt, dim3(MTOT), dim3(256), 0, stream, Wh, Wf, Wg, bh, bf, bg, Wb, bcat);
  hipLaunchKernelGGL(proj_all, dim3(BATCH * 64), dim3(512), 0, stream, x, Wb, bcat, Fw, Gw, Hw);

  if (ws_size >= NEED) {
    hipLaunchKernelGGL(attn_full, dim3(BATCH * 64), dim3(1024), 0, stream, Fw, Gw, Hw, out);
  } else {
    hipLaunchKernelGGL(attn_kernel, dim3(BATCH * 64), dim3(512), 0, stream, Fw, Gw, Hw, out);
  }
}

// Round 20
// 84.470 us; speedup vs baseline: 1.1749x; 1.1749x over previous
//
#include <hip/hip_runtime.h>
#include <hip/hip_bf16.h>
#include <math.h>

#define BATCH 4
#define CIN   256
#define DQK   32
#define NPIX  4096
#define MTOT  320

typedef __attribute__((ext_vector_type(4))) float f32x4;
typedef __attribute__((ext_vector_type(8))) short bf16x8;
typedef __attribute__((ext_vector_type(4))) unsigned int u32x4;

__device__ __forceinline__ unsigned short f2bf(float f) {
  unsigned u = __builtin_bit_cast(unsigned, f);
  u += 0x7FFFu + ((u >> 16) & 1u);   // RNE
  return (unsigned short)(u >> 16);
}
__device__ __forceinline__ unsigned pk2(float a, float b) {
  return (unsigned)f2bf(a) | ((unsigned)f2bf(b) << 16);
}
__device__ __forceinline__ void wait_vm2_lgkm0() { asm volatile("s_waitcnt vmcnt(2) lgkmcnt(0)" ::: "memory"); }
__device__ __forceinline__ void wait_vm0_lgkm0() { asm volatile("s_waitcnt vmcnt(0) lgkmcnt(0)" ::: "memory"); }

#define GLD16(GP, LP) \
  __builtin_amdgcn_global_load_lds((const __attribute__((address_space(1))) void*)(GP), \
                                   (__attribute__((address_space(3))) void*)(LP), 16, 0, 0)

// ---------------- W convert ----------------
__global__ void wcvt(const float* __restrict__ Wh, const float* __restrict__ Wf,
                     const float* __restrict__ Wg,
                     const float* __restrict__ bh, const float* __restrict__ bf,
                     const float* __restrict__ bg,
                     unsigned short* __restrict__ Wb, float* __restrict__ bcat) {
  const int r = blockIdx.x;
  const int c = threadIdx.x;
  const float* src = (r < 256) ? &Wh[r * CIN] : (r < 288) ? &Wf[(r - 256) * CIN] : &Wg[(r - 288) * CIN];
  Wb[r * CIN + c] = f2bf(src[c]);
  if (c == 0)
    bcat[r] = (r < 256) ? bh[r] : (r < 288) ? bf[r - 256] : bg[r - 288];
}

// ---------------- fused projection GEMM (r2-proven) ----------------
#define XPAD 4
__launch_bounds__(512, 1)
__global__ void proj_all(const float* __restrict__ x, const unsigned short* __restrict__ Wb,
                         const float* __restrict__ bcat,
                         unsigned short* __restrict__ F, unsigned short* __restrict__ G,
                         unsigned short* __restrict__ H) {
  __shared__ unsigned short Xs[64 * (CIN + XPAD)];

  const int bid = blockIdx.x;
  const int b = bid >> 6;
  const int n0 = (bid & 63) << 6;
  const int t = threadIdx.x;
  const int lane = t & 63;
  const int w = t >> 6;

  const float* __restrict__ xb = x + (size_t)b * CIN * NPIX + n0;
#pragma unroll
  for (int p = 0; p < 16; ++p) {
    const int k = p * 16 + w * 2;
    const float a0 = xb[(size_t)k * NPIX + lane];
    const float a1 = xb[(size_t)(k + 1) * NPIX + lane];
    const unsigned pk = (unsigned)f2bf(a0) | ((unsigned)f2bf(a1) << 16);
    *(unsigned*)((char*)Xs + lane * (CIN + XPAD) * 2 + k * 2) = pk;
  }
  __syncthreads();

  const int l16 = lane & 15, lhi = lane >> 4;
  const int wm = w >> 1;
  const int wn = w & 1;

  const f32x4 fzero = {0.f, 0.f, 0.f, 0.f};
  f32x4 acc[5][2];
#pragma unroll
  for (int i = 0; i < 5; ++i)
#pragma unroll
    for (int j = 0; j < 2; ++j) acc[i][j] = fzero;

#pragma unroll
  for (int ks = 0; ks < 8; ++ks) {
    bf16x8 bx[2];
#pragma unroll
    for (int j = 0; j < 2; ++j)
      bx[j] = *(const bf16x8*)&Xs[(wn * 32 + j * 16 + l16) * (CIN + XPAD) + ks * 32 + lhi * 8];
#pragma unroll
    for (int i = 0; i < 5; ++i) {
      const bf16x8 aw = *(const bf16x8*)(Wb + (size_t)(wm * 80 + i * 16 + l16) * CIN + ks * 32 + lhi * 8);
#pragma unroll
      for (int j = 0; j < 2; ++j)
        acc[i][j] = __builtin_amdgcn_mfma_f32_16x16x32_bf16(aw, bx[j], acc[i][j], 0, 0, 0);
    }
  }

#pragma unroll
  for (int i = 0; i < 5; ++i) {
    const int MT = wm * 5 + i;
    const int m0 = MT * 16;
    const f32x4 bias = *(const f32x4*)&bcat[m0 + lhi * 4];
#pragma unroll
    for (int j = 0; j < 2; ++j) {
      const int n = n0 + wn * 32 + j * 16 + l16;
      f32x4 v = acc[i][j];
      v.x += bias.x; v.y += bias.y; v.z += bias.z; v.w += bias.w;
      if (MT < 16) {
        const int c0 = m0 + lhi * 4;
        unsigned short* dst = H + ((size_t)b * CIN + c0) * NPIX + n;
        dst[0 * NPIX] = f2bf(v.x);
        dst[1 * NPIX] = f2bf(v.y);
        dst[2 * NPIX] = f2bf(v.z);
        dst[3 * NPIX] = f2bf(v.w);
      } else {
        unsigned short* dst = (MT < 18) ? F : G;
        const int d0 = ((MT - 16) & 1) * 16 + lhi * 4;
        uint2 pk;
        pk.x = (unsigned)f2bf(v.x) | ((unsigned)f2bf(v.y) << 16);
        pk.y = (unsigned)f2bf(v.z) | ((unsigned)f2bf(v.w) << 16);
        *(uint2*)(dst + ((size_t)b * NPIX + n) * DQK + d0) = pk;
      }
    }
  }
}

// ---------------- key-split flash attention (r17-proven best) ----------------
// grid 256 (4b x 32qt x 2split, slab swizzle bid&7) x 16 waves (1024 thr). QT=128.
// Wave (mg 0..3, cs 0..3): QK = its 32 queries x 16-key slice (2 MFMA, no dup);
// PV = 64 channels x 32 queries (16 MFMA). K/V triple-buffered via
// global_load_lds (V: 2x16B/thread, K: waves 12-15, K issued FIRST).
// ONE {vmcnt(2)+lgkm0; barrier} per tile (ledger: wait keeps V(t+1)x2, retires
// V(t)+K(t+1)). P parity-double-buffered. M=0 softmax, __expf.
#define BNK  64
#define KEYS 2048
#define NTILE (KEYS / BNK)   // 32

__launch_bounds__(1024, 1)
__global__ void attn_split(const unsigned short* __restrict__ F,
                           const unsigned short* __restrict__ G,
                           const unsigned short* __restrict__ H,
                           unsigned short* __restrict__ Ap, float* __restrict__ Lp) {
  __shared__ unsigned short Kl[3][64][32];       // [buf][n][32d]  linear 12 KB
  __shared__ unsigned short Vl[3][256][64];      // [buf][c][64n]  linear 96 KB
  __shared__ unsigned short Pl[2][4][32][72];    // [parity][mg][q][64n+pad] 36.9 KB

  const int bid = blockIdx.x;
  const int slab = bid & 7;                      // (b,split) -> XCD under round-robin
  const int b = slab >> 1;
  const int split = slab & 1;
  const int qt = bid >> 3;                       // 0..31
  const int t = threadIdx.x;
  const int lane = t & 63, w = t >> 6;           // w 0..15
  const int l16 = lane & 15, lhi = lane >> 4;
  const int mg = w >> 2, cs = w & 3;

  const unsigned short* Fb = F + (size_t)b * NPIX * DQK;
  const unsigned short* Gb = G + (size_t)b * NPIX * DQK;
  const unsigned short* Hb = H + (size_t)b * CIN * NPIX;
  const int nb0 = split * KEYS;
  const int q0 = qt * 128 + mg * 32;             // wave's 32-query base

  const f32x4 fzero = {0.f, 0.f, 0.f, 0.f};

  // Q fragments (B-operand): col m = l16, k = lhi*8..+7
  bf16x8 qf[2];
#pragma unroll
  for (int mt = 0; mt < 2; ++mt)
    qf[mt] = *(const bf16x8*)(Gb + (size_t)(q0 + mt * 16 + l16) * DQK + lhi * 8);

  f32x4 acc[4][2];
#pragma unroll
  for (int ct = 0; ct < 4; ++ct)
#pragma unroll
    for (int mt = 0; mt < 2; ++mt) acc[ct][mt] = fzero;
  float Lacc[2] = {0.f, 0.f};

  // async staging sources (pre-swizzled; involution row&7 == lane>>3 preserved):
  const char* vsrc = (const char*)Hb + ((size_t)(8 * w + (lane >> 3)) * NPIX + nb0) * 2
                   + (((lane & 7) ^ (lane >> 3)) * 16);
  const int kw = (w >= 12) ? (w - 12) : 0;
  const char* ksrc = (const char*)Fb + ((size_t)(nb0 + 16 * kw + (lane >> 2)) * DQK) * 2
                   + (((lane & 3) ^ ((lane >> 2) & 3)) * 16);

// K issued FIRST so vmcnt(2) (keeping the 2 newer V loads) retires it on schedule
#define ISSUE(TT) do {                                                           \
    const int bu_ = (TT) % 3;                                                    \
    if (w >= 12)                                                                 \
      GLD16(ksrc + (size_t)(TT) * 64 * DQK * 2, &Kl[bu_][16 * kw][0]);           \
    _Pragma("unroll")                                                            \
    for (int i_ = 0; i_ < 2; ++i_)                                               \
      GLD16(vsrc + (size_t)i_ * 128 * NPIX * 2 + (size_t)(TT) * 128,             \
            &Vl[bu_][i_ * 128 + 8 * w][0]);                                      \
  } while (0)

  // QK (2 MFMA) + softmax -> P slice to Pl[PAR][mg]
#define QKSM(BUF3, PAR) do {                                                     \
    const unsigned short* kb_ = &Kl[BUF3][0][0];                                 \
    const bf16x8 kf_ = *(const bf16x8*)(kb_ + (cs * 16 + l16) * 32 + ((lhi ^ (l16 & 3)) * 8)); \
    f32x4 s_[2];                                                                 \
    _Pragma("unroll")                                                            \
    for (int mt_ = 0; mt_ < 2; ++mt_)                                            \
      s_[mt_] = __builtin_amdgcn_mfma_f32_16x16x32_bf16(kf_, qf[mt_], fzero, 0, 0, 0); \
    _Pragma("unroll")                                                            \
    for (int mt_ = 0; mt_ < 2; ++mt_) {                                          \
      const float p0 = __expf(s_[mt_][0]), p1 = __expf(s_[mt_][1]);              \
      const float p2 = __expf(s_[mt_][2]), p3 = __expf(s_[mt_][3]);              \
      Lacc[mt_] += (p0 + p1) + (p2 + p3);                                        \
      uint2 pk_; pk_.x = pk2(p0, p1); pk_.y = pk2(p2, p3);                       \
      *(uint2*)&Pl[PAR][mg][mt_ * 16 + l16][cs * 16 + lhi * 4] = pk_;            \
    }                                                                            \
  } while (0)

#define PVACC(BUF3, PF) do {                                                     \
    const unsigned short* vb_ = &Vl[BUF3][0][0];                                 \
    __builtin_amdgcn_s_setprio(1);                                               \
    _Pragma("unroll")                                                            \
    for (int kk_ = 0; kk_ < 2; ++kk_)                                            \
      _Pragma("unroll")                                                          \
      for (int ct_ = 0; ct_ < 4; ++ct_) {                                        \
        const bf16x8 vf_ = *(const bf16x8*)(vb_ + (cs * 64 + ct_ * 16 + l16) * 64 \
                            + (((4 * kk_ + lhi) ^ (l16 & 7)) * 8));              \
        _Pragma("unroll")                                                        \
        for (int mt_ = 0; mt_ < 2; ++mt_)                                        \
          acc[ct_][mt_] = __builtin_amdgcn_mfma_f32_16x16x32_bf16(vf_, PF[mt_][kk_], acc[ct_][mt_], 0, 0, 0); \
      }                                                                          \
    __builtin_amdgcn_s_setprio(0);                                               \
  } while (0)

  // prologue: tiles 0,1 in flight; vmcnt(2) retires {K0,V0,K1}, keeps V1x2
  ISSUE(0); ISSUE(1);
  wait_vm2_lgkm0();
  __builtin_amdgcn_s_barrier();
  asm volatile("" ::: "memory");
  QKSM(0, 0);

  for (int tt = 0; tt < NTILE; ++tt) {
    const int par = tt & 1;
    // the ONLY barrier per tile
    if (tt == NTILE - 1) wait_vm0_lgkm0(); else wait_vm2_lgkm0();
    __builtin_amdgcn_s_barrier();
    asm volatile("" ::: "memory");
    // buffer (tt+2)%3 was last read at iter tt-1 -> free now
    if (tt + 2 < NTILE) ISSUE(tt + 2);
    // pf: P(tt) reads issue early; latency covered by QKSM(tt+1)
    bf16x8 pf[2][2];
#pragma unroll
    for (int mt = 0; mt < 2; ++mt)
#pragma unroll
      for (int kk = 0; kk < 2; ++kk)
        pf[mt][kk] = *(const bf16x8*)&Pl[par][mg][mt * 16 + l16][kk * 32 + lhi * 8];
    if (tt + 1 < NTILE) QKSM((tt + 1) % 3, par ^ 1);
    PVACC(tt % 3, pf);
  }
#undef ISSUE
#undef QKSM
#undef PVACC

  // epilogue: L partials + unnormalized A (bf16)
#pragma unroll
  for (int mt = 0; mt < 2; ++mt) {
    float L = Lacc[mt];
    L += __shfl_xor(L, 16, 64);
    L += __shfl_xor(L, 32, 64);
    if (lhi == 0)
      Lp[((size_t)split * 4 + cs) * (4 * NPIX) + (size_t)b * NPIX + q0 + mt * 16 + l16] = L;
  }
#pragma unroll
  for (int ct = 0; ct < 4; ++ct)
#pragma unroll
    for (int mt = 0; mt < 2; ++mt) {
      const int c = cs * 64 + ct * 16 + lhi * 4;
      const int q = q0 + mt * 16 + l16;
      unsigned short* dst = Ap + (((size_t)split * 4 + b) * CIN + c) * NPIX + q;
#pragma unroll
      for (int v = 0; v < 4; ++v) dst[(size_t)v * NPIX] = f2bf(acc[ct][mt][v]);
    }
}

// fused combine: out[b][c][q] = (A0 + A1) / sum_i Lp[i][b][q]
// (Lp is 512KB, L2-resident; recomputing the 8-way sum per (c) is cheap and
// saves the combineL launch + Linv round-trip)
__global__ void combine(const unsigned short* __restrict__ Ap, const float* __restrict__ Lp,
                        float* __restrict__ out) {
  const size_t base = ((size_t)blockIdx.x * 256 + threadIdx.x) * 8;
  const int b = (int)(base / ((size_t)CIN * NPIX));
  const int q = (int)(base % NPIX);
  const u32x4 a0 = *(const u32x4*)(Ap + base);
  const u32x4 a1 = *(const u32x4*)(Ap + (size_t)4 * CIN * NPIX + base);
  const size_t lbase = (size_t)b * NPIX + q;
  float lv[8];
#pragma unroll
  for (int j = 0; j < 8; ++j) {
    float s = 0.f;
#pragma unroll
    for (int i = 0; i < 8; ++i) s += Lp[(size_t)i * (4 * NPIX) + lbase + j];
    lv[j] = 1.f / s;
  }
  float r[8];
#pragma unroll
  for (int i = 0; i < 4; ++i) {
    const float x0 = __builtin_bit_cast(float, (a0[i] & 0xFFFFu) << 16) +
                     __builtin_bit_cast(float, (a1[i] & 0xFFFFu) << 16);
    const float x1 = __builtin_bit_cast(float, (a0[i] & 0xFFFF0000u)) +
                     __builtin_bit_cast(float, (a1[i] & 0xFFFF0000u));
    r[2 * i] = x0 * lv[2 * i];
    r[2 * i + 1] = x1 * lv[2 * i + 1];
  }
  *(f32x4*)&out[base] = *(f32x4*)&r[0];
  *(f32x4*)&out[base + 4] = *(f32x4*)&r[4];
}

// ---------------- fallback flash attention (r2-proven; ws too small) ----------------
#define BN 32
__launch_bounds__(512, 2)
__global__ void attn_kernel(const unsigned short* __restrict__ F,
                            const unsigned short* __restrict__ G,
                            const unsigned short* __restrict__ H,
                            float* __restrict__ out) {
  __shared__ unsigned short Klds[32 * 40];
  __shared__ unsigned short Vlds[256 * 40];
  __shared__ unsigned short Plds[8][32 * 40];

  const int bid = blockIdx.x;
  const int b = bid >> 6;
  const int t = threadIdx.x;
  const int lane = t & 63;
  const int w = t >> 6;
  const int l16 = lane & 15;
  const int lhi = lane >> 4;
  const int m0 = ((bid & 63) << 6) + ((w >> 2) << 5);
  const int c0 = (w & 3) << 6;

  const f32x4 fzero = {0.f, 0.f, 0.f, 0.f};

  bf16x8 qf[2];
#pragma unroll
  for (int mt = 0; mt < 2; ++mt)
    qf[mt] = *(const bf16x8*)(G + ((size_t)b * NPIX + m0 + mt * 16 + l16) * DQK + lhi * 8);

  f32x4 acc[4][2];
#pragma unroll
  for (int ct = 0; ct < 4; ++ct)
#pragma unroll
    for (int mt = 0; mt < 2; ++mt) acc[ct][mt] = fzero;
  float Mr[2] = {-INFINITY, -INFINITY};
  float Lr[2] = {0.f, 0.f};

  const unsigned short* Fb = F + (size_t)b * NPIX * DQK;
  const unsigned short* Hb = H + (size_t)b * CIN * NPIX;
  unsigned short* Pw = &Plds[w][0];

  for (int n0 = 0; n0 < NPIX; n0 += BN) {
    __syncthreads();
    if (t < 128) {
      const int nr = t >> 2, sl = t & 3;
      *(u32x4*)&Klds[nr * 40 + sl * 8] = *(const u32x4*)(Fb + (size_t)(n0 + nr) * DQK + sl * 8);
    }
#pragma unroll
    for (int i = 0; i < 2; ++i) {
      const int q = t + i * 512;
      const int cr = q >> 2, sl = q & 3;
      *(u32x4*)&Vlds[cr * 40 + sl * 8] = *(const u32x4*)(Hb + (size_t)cr * NPIX + n0 + sl * 8);
    }
    __syncthreads();

    bf16x8 kf[2];
#pragma unroll
    for (int nts = 0; nts < 2; ++nts)
      kf[nts] = *(const bf16x8*)&Klds[(nts * 16 + l16) * 40 + lhi * 8];
    f32x4 s[2][2];
#pragma unroll
    for (int mt = 0; mt < 2; ++mt)
#pragma unroll
      for (int nts = 0; nts < 2; ++nts)
        s[mt][nts] = __builtin_amdgcn_mfma_f32_16x16x32_bf16(kf[nts], qf[mt], fzero, 0, 0, 0);

#pragma unroll
    for (int mt = 0; mt < 2; ++mt) {
      float tmax = s[mt][0][0];
#pragma unroll
      for (int v = 1; v < 4; ++v) tmax = fmaxf(tmax, s[mt][0][v]);
#pragma unroll
      for (int v = 0; v < 4; ++v) tmax = fmaxf(tmax, s[mt][1][v]);
      tmax = fmaxf(tmax, __shfl_xor(tmax, 16, 64));
      tmax = fmaxf(tmax, __shfl_xor(tmax, 32, 64));
      const float newM = fmaxf(Mr[mt], tmax);
      const float rescale = __expf(Mr[mt] - newM);
      Mr[mt] = newM;
      float p[2][4];
      float psum = 0.f;
#pragma unroll
      for (int nts = 0; nts < 2; ++nts)
#pragma unroll
        for (int v = 0; v < 4; ++v) {
          p[nts][v] = __expf(s[mt][nts][v] - newM);
          psum += p[nts][v];
        }
      psum += __shfl_xor(psum, 16, 64);
      psum += __shfl_xor(psum, 32, 64);
      Lr[mt] = Lr[mt] * rescale + psum;
#pragma unroll
      for (int ct = 0; ct < 4; ++ct) acc[ct][mt] *= rescale;
#pragma unroll
      for (int nts = 0; nts < 2; ++nts) {
        uint2 pkv;
        pkv.x = (unsigned)f2bf(p[nts][0]) | ((unsigned)f2bf(p[nts][1]) << 16);
        pkv.y = (unsigned)f2bf(p[nts][2]) | ((unsigned)f2bf(p[nts][3]) << 16);
        *(uint2*)&Pw[(mt * 16 + l16) * 40 + nts * 16 + lhi * 4] = pkv;
      }
    }
    asm volatile("" ::: "memory");

    bf16x8 pf[2];
#pragma unroll
    for (int mt = 0; mt < 2; ++mt)
      pf[mt] = *(const bf16x8*)&Pw[(mt * 16 + l16) * 40 + lhi * 8];
#pragma unroll
    for (int ct = 0; ct < 4; ++ct) {
      const bf16x8 vf = *(const bf16x8*)&Vlds[(c0 + ct * 16 + l16) * 40 + lhi * 8];
#pragma unroll
      for (int mt = 0; mt < 2; ++mt)
        acc[ct][mt] = __builtin_amdgcn_mfma_f32_16x16x32_bf16(vf, pf[mt], acc[ct][mt], 0, 0, 0);
    }
  }

#pragma unroll
  for (int mt = 0; mt < 2; ++mt) {
    const float invL = 1.f / Lr[mt];
    const int m = m0 + mt * 16 + l16;
#pragma unroll
    for (int ct = 0; ct < 4; ++ct)
#pragma unroll
      for (int v = 0; v < 4; ++v) {
        const int c = c0 + ct * 16 + lhi * 4 + v;
        out[((size_t)b * CIN + c) * NPIX + m] = acc[ct][mt][v] * invL;
      }
  }
}

extern "C" void kernel_launch(void* const* d_in, const int* in_sizes, int n_in,
                              void* d_out, int out_size, void* d_ws, size_t ws_size,
                              hipStream_t stream) {
  (void)in_sizes; (void)n_in; (void)out_size;
  const float* x  = (const float*)d_in[0];
  const float* Wf = (const float*)d_in[1];
  const float* bf = (const float*)d_in[2];
  const float* Wg = (const float*)d_in[3];
  const float* bg = (const float*)d_in[4];
  const float* Wh = (const float*)d_in[5];
  const float* bh = (const float*)d_in[6];
  float* out = (float*)d_out;

  unsigned short* Fw = (unsigned short*)d_ws;
  unsigned short* Gw = Fw + (size_t)BATCH * NPIX * DQK;
  unsigned short* Hw = Gw + (size_t)BATCH * NPIX * DQK;
  unsigned short* Wb = Hw + (size_t)BATCH * CIN * NPIX;
  float* bcat = (float*)(Wb + (size_t)MTOT * CIN);
  unsigned short* Apart = (unsigned short*)(bcat + MTOT);
  float* Lpart = (float*)(Apart + (size_t)2 * BATCH * CIN * NPIX);
  const size_t NEED = (size_t)((char*)(Lpart + (size_t)8 * BATCH * NPIX) - (char*)d_ws);

  hipLaunchKernelGGL(wcvt, dim3(MTOT), dim3(256), 0, stream, Wh, Wf, Wg, bh, bf, bg, Wb, bcat);
  hipLaunchKernelGGL(proj_all, dim3(BATCH * 64), dim3(512), 0, stream, x, Wb, bcat, Fw, Gw, Hw);

  if (ws_size >= NEED) {
    hipLaunchKernelGGL(attn_split, dim3(BATCH * 32 * 2), dim3(1024), 0, stream, Fw, Gw, Hw, Apart, Lpart);
    hipLaunchKernelGGL(combine, dim3((size_t)BATCH * CIN * NPIX / 8 / 256), dim3(256), 0, stream, Apart, Lpart, out);
  } else {
    hipLaunchKernelGGL(attn_kernel, dim3(BATCH * 64), dim3(512), 0, stream, Fw, Gw, Hw, out);
  }
}

// Round 21
// 83.036 us; speedup vs baseline: 1.1952x; 1.0173x over previous
//
#include <hip/hip_runtime.h>
#include <hip/hip_bf16.h>
#include <math.h>

#define BATCH 4
#define CIN   256
#define DQK   32
#define NPIX  4096
#define MTOT  320

typedef __attribute__((ext_vector_type(4))) float f32x4;
typedef __attribute__((ext_vector_type(8))) short bf16x8;
typedef __attribute__((ext_vector_type(4))) unsigned int u32x4;

__device__ __forceinline__ unsigned short f2bf(float f) {
  unsigned u = __builtin_bit_cast(unsigned, f);
  u += 0x7FFFu + ((u >> 16) & 1u);   // RNE
  return (unsigned short)(u >> 16);
}
__device__ __forceinline__ unsigned pk2(float a, float b) {
  return (unsigned)f2bf(a) | ((unsigned)f2bf(b) << 16);
}
__device__ __forceinline__ void wait_vm2_lgkm0() { asm volatile("s_waitcnt vmcnt(2) lgkmcnt(0)" ::: "memory"); }
__device__ __forceinline__ void wait_vm0_lgkm0() { asm volatile("s_waitcnt vmcnt(0) lgkmcnt(0)" ::: "memory"); }

#define GLD16(GP, LP) \
  __builtin_amdgcn_global_load_lds((const __attribute__((address_space(1))) void*)(GP), \
                                   (__attribute__((address_space(3))) void*)(LP), 16, 0, 0)

// ---------------- W convert ----------------
__global__ void wcvt(const float* __restrict__ Wh, const float* __restrict__ Wf,
                     const float* __restrict__ Wg,
                     const float* __restrict__ bh, const float* __restrict__ bf,
                     const float* __restrict__ bg,
                     unsigned short* __restrict__ Wb, float* __restrict__ bcat) {
  const int r = blockIdx.x;
  const int c = threadIdx.x;
  const float* src = (r < 256) ? &Wh[r * CIN] : (r < 288) ? &Wf[(r - 256) * CIN] : &Wg[(r - 288) * CIN];
  Wb[r * CIN + c] = f2bf(src[c]);
  if (c == 0)
    bcat[r] = (r < 256) ? bh[r] : (r < 288) ? bf[r - 256] : bg[r - 288];
}

// ---------------- fused projection GEMM (r2-proven) ----------------
#define XPAD 4
__launch_bounds__(512, 1)
__global__ void proj_all(const float* __restrict__ x, const unsigned short* __restrict__ Wb,
                         const float* __restrict__ bcat,
                         unsigned short* __restrict__ F, unsigned short* __restrict__ G,
                         unsigned short* __restrict__ H) {
  __shared__ unsigned short Xs[64 * (CIN + XPAD)];

  const int bid = blockIdx.x;
  const int b = bid >> 6;
  const int n0 = (bid & 63) << 6;
  const int t = threadIdx.x;
  const int lane = t & 63;
  const int w = t >> 6;

  const float* __restrict__ xb = x + (size_t)b * CIN * NPIX + n0;
#pragma unroll
  for (int p = 0; p < 16; ++p) {
    const int k = p * 16 + w * 2;
    const float a0 = xb[(size_t)k * NPIX + lane];
    const float a1 = xb[(size_t)(k + 1) * NPIX + lane];
    const unsigned pk = (unsigned)f2bf(a0) | ((unsigned)f2bf(a1) << 16);
    *(unsigned*)((char*)Xs + lane * (CIN + XPAD) * 2 + k * 2) = pk;
  }
  __syncthreads();

  const int l16 = lane & 15, lhi = lane >> 4;
  const int wm = w >> 1;
  const int wn = w & 1;

  const f32x4 fzero = {0.f, 0.f, 0.f, 0.f};
  f32x4 acc[5][2];
#pragma unroll
  for (int i = 0; i < 5; ++i)
#pragma unroll
    for (int j = 0; j < 2; ++j) acc[i][j] = fzero;

#pragma unroll
  for (int ks = 0; ks < 8; ++ks) {
    bf16x8 bx[2];
#pragma unroll
    for (int j = 0; j < 2; ++j)
      bx[j] = *(const bf16x8*)&Xs[(wn * 32 + j * 16 + l16) * (CIN + XPAD) + ks * 32 + lhi * 8];
#pragma unroll
    for (int i = 0; i < 5; ++i) {
      const bf16x8 aw = *(const bf16x8*)(Wb + (size_t)(wm * 80 + i * 16 + l16) * CIN + ks * 32 + lhi * 8);
#pragma unroll
      for (int j = 0; j < 2; ++j)
        acc[i][j] = __builtin_amdgcn_mfma_f32_16x16x32_bf16(aw, bx[j], acc[i][j], 0, 0, 0);
    }
  }

#pragma unroll
  for (int i = 0; i < 5; ++i) {
    const int MT = wm * 5 + i;
    const int m0 = MT * 16;
    const f32x4 bias = *(const f32x4*)&bcat[m0 + lhi * 4];
#pragma unroll
    for (int j = 0; j < 2; ++j) {
      const int n = n0 + wn * 32 + j * 16 + l16;
      f32x4 v = acc[i][j];
      v.x += bias.x; v.y += bias.y; v.z += bias.z; v.w += bias.w;
      if (MT < 16) {
        const int c0 = m0 + lhi * 4;
        unsigned short* dst = H + ((size_t)b * CIN + c0) * NPIX + n;
        dst[0 * NPIX] = f2bf(v.x);
        dst[1 * NPIX] = f2bf(v.y);
        dst[2 * NPIX] = f2bf(v.z);
        dst[3 * NPIX] = f2bf(v.w);
      } else {
        unsigned short* dst = (MT < 18) ? F : G;
        const int d0 = ((MT - 16) & 1) * 16 + lhi * 4;
        uint2 pk;
        pk.x = (unsigned)f2bf(v.x) | ((unsigned)f2bf(v.y) << 16);
        pk.y = (unsigned)f2bf(v.z) | ((unsigned)f2bf(v.w) << 16);
        *(uint2*)(dst + ((size_t)b * NPIX + n) * DQK + d0) = pk;
      }
    }
  }
}

// ---------------- key-split flash attention (r17-proven best) ----------------
// grid 256 (4b x 32qt x 2split, slab swizzle bid&7) x 16 waves (1024 thr). QT=128.
// Wave (mg 0..3, cs 0..3): QK = its 32 queries x 16-key slice (2 MFMA, no dup);
// PV = 64 channels x 32 queries (16 MFMA). K/V triple-buffered via
// global_load_lds (V: 2x16B/thread, K: waves 12-15, K issued FIRST).
// ONE {vmcnt(2)+lgkm0; barrier} per tile (ledger: wait keeps V(t+1)x2, retires
// V(t)+K(t+1)). P parity-double-buffered. M=0 softmax, __expf.
#define BNK  64
#define KEYS 2048
#define NTILE (KEYS / BNK)   // 32

__launch_bounds__(1024, 1)
__global__ void attn_split(const unsigned short* __restrict__ F,
                           const unsigned short* __restrict__ G,
                           const unsigned short* __restrict__ H,
                           unsigned short* __restrict__ Ap, float* __restrict__ Lp) {
  __shared__ unsigned short Kl[3][64][32];       // [buf][n][32d]  linear 12 KB
  __shared__ unsigned short Vl[3][256][64];      // [buf][c][64n]  linear 96 KB
  __shared__ unsigned short Pl[2][4][32][72];    // [parity][mg][q][64n+pad] 36.9 KB

  const int bid = blockIdx.x;
  const int slab = bid & 7;                      // (b,split) -> XCD under round-robin
  const int b = slab >> 1;
  const int split = slab & 1;
  const int qt = bid >> 3;                       // 0..31
  const int t = threadIdx.x;
  const int lane = t & 63, w = t >> 6;           // w 0..15
  const int l16 = lane & 15, lhi = lane >> 4;
  const int mg = w >> 2, cs = w & 3;

  const unsigned short* Fb = F + (size_t)b * NPIX * DQK;
  const unsigned short* Gb = G + (size_t)b * NPIX * DQK;
  const unsigned short* Hb = H + (size_t)b * CIN * NPIX;
  const int nb0 = split * KEYS;
  const int q0 = qt * 128 + mg * 32;             // wave's 32-query base

  const f32x4 fzero = {0.f, 0.f, 0.f, 0.f};

  // Q fragments (B-operand): col m = l16, k = lhi*8..+7
  bf16x8 qf[2];
#pragma unroll
  for (int mt = 0; mt < 2; ++mt)
    qf[mt] = *(const bf16x8*)(Gb + (size_t)(q0 + mt * 16 + l16) * DQK + lhi * 8);

  f32x4 acc[4][2];
#pragma unroll
  for (int ct = 0; ct < 4; ++ct)
#pragma unroll
    for (int mt = 0; mt < 2; ++mt) acc[ct][mt] = fzero;
  float Lacc[2] = {0.f, 0.f};

  // async staging sources (pre-swizzled; involution row&7 == lane>>3 preserved):
  const char* vsrc = (const char*)Hb + ((size_t)(8 * w + (lane >> 3)) * NPIX + nb0) * 2
                   + (((lane & 7) ^ (lane >> 3)) * 16);
  const int kw = (w >= 12) ? (w - 12) : 0;
  const char* ksrc = (const char*)Fb + ((size_t)(nb0 + 16 * kw + (lane >> 2)) * DQK) * 2
                   + (((lane & 3) ^ ((lane >> 2) & 3)) * 16);

// K issued FIRST so vmcnt(2) (keeping the 2 newer V loads) retires it on schedule
#define ISSUE(TT) do {                                                           \
    const int bu_ = (TT) % 3;                                                    \
    if (w >= 12)                                                                 \
      GLD16(ksrc + (size_t)(TT) * 64 * DQK * 2, &Kl[bu_][16 * kw][0]);           \
    _Pragma("unroll")                                                            \
    for (int i_ = 0; i_ < 2; ++i_)                                               \
      GLD16(vsrc + (size_t)i_ * 128 * NPIX * 2 + (size_t)(TT) * 128,             \
            &Vl[bu_][i_ * 128 + 8 * w][0]);                                      \
  } while (0)

  // QK (2 MFMA) + softmax -> P slice to Pl[PAR][mg]
#define QKSM(BUF3, PAR) do {                                                     \
    const unsigned short* kb_ = &Kl[BUF3][0][0];                                 \
    const bf16x8 kf_ = *(const bf16x8*)(kb_ + (cs * 16 + l16) * 32 + ((lhi ^ (l16 & 3)) * 8)); \
    f32x4 s_[2];                                                                 \
    _Pragma("unroll")                                                            \
    for (int mt_ = 0; mt_ < 2; ++mt_)                                            \
      s_[mt_] = __builtin_amdgcn_mfma_f32_16x16x32_bf16(kf_, qf[mt_], fzero, 0, 0, 0); \
    _Pragma("unroll")                                                            \
    for (int mt_ = 0; mt_ < 2; ++mt_) {                                          \
      const float p0 = __expf(s_[mt_][0]), p1 = __expf(s_[mt_][1]);              \
      const float p2 = __expf(s_[mt_][2]), p3 = __expf(s_[mt_][3]);              \
      Lacc[mt_] += (p0 + p1) + (p2 + p3);                                        \
      uint2 pk_; pk_.x = pk2(p0, p1); pk_.y = pk2(p2, p3);                       \
      *(uint2*)&Pl[PAR][mg][mt_ * 16 + l16][cs * 16 + lhi * 4] = pk_;            \
    }                                                                            \
  } while (0)

#define PVACC(BUF3, PF) do {                                                     \
    const unsigned short* vb_ = &Vl[BUF3][0][0];                                 \
    __builtin_amdgcn_s_setprio(1);                                               \
    _Pragma("unroll")                                                            \
    for (int kk_ = 0; kk_ < 2; ++kk_)                                            \
      _Pragma("unroll")                                                          \
      for (int ct_ = 0; ct_ < 4; ++ct_) {                                        \
        const bf16x8 vf_ = *(const bf16x8*)(vb_ + (cs * 64 + ct_ * 16 + l16) * 64 \
                            + (((4 * kk_ + lhi) ^ (l16 & 7)) * 8));              \
        _Pragma("unroll")                                                        \
        for (int mt_ = 0; mt_ < 2; ++mt_)                                        \
          acc[ct_][mt_] = __builtin_amdgcn_mfma_f32_16x16x32_bf16(vf_, PF[mt_][kk_], acc[ct_][mt_], 0, 0, 0); \
      }                                                                          \
    __builtin_amdgcn_s_setprio(0);                                               \
  } while (0)

  // prologue: tiles 0,1 in flight; vmcnt(2) retires {K0,V0,K1}, keeps V1x2
  ISSUE(0); ISSUE(1);
  wait_vm2_lgkm0();
  __builtin_amdgcn_s_barrier();
  asm volatile("" ::: "memory");
  QKSM(0, 0);

  for (int tt = 0; tt < NTILE; ++tt) {
    const int par = tt & 1;
    // the ONLY barrier per tile
    if (tt == NTILE - 1) wait_vm0_lgkm0(); else wait_vm2_lgkm0();
    __builtin_amdgcn_s_barrier();
    asm volatile("" ::: "memory");
    // buffer (tt+2)%3 was last read at iter tt-1 -> free now
    if (tt + 2 < NTILE) ISSUE(tt + 2);
    // pf: P(tt) reads issue early; latency covered by QKSM(tt+1)
    bf16x8 pf[2][2];
#pragma unroll
    for (int mt = 0; mt < 2; ++mt)
#pragma unroll
      for (int kk = 0; kk < 2; ++kk)
        pf[mt][kk] = *(const bf16x8*)&Pl[par][mg][mt * 16 + l16][kk * 32 + lhi * 8];
    if (tt + 1 < NTILE) QKSM((tt + 1) % 3, par ^ 1);
    PVACC(tt % 3, pf);
  }
#undef ISSUE
#undef QKSM
#undef PVACC

  // epilogue: L partials + unnormalized A (bf16)
#pragma unroll
  for (int mt = 0; mt < 2; ++mt) {
    float L = Lacc[mt];
    L += __shfl_xor(L, 16, 64);
    L += __shfl_xor(L, 32, 64);
    if (lhi == 0)
      Lp[((size_t)split * 4 + cs) * (4 * NPIX) + (size_t)b * NPIX + q0 + mt * 16 + l16] = L;
  }
#pragma unroll
  for (int ct = 0; ct < 4; ++ct)
#pragma unroll
    for (int mt = 0; mt < 2; ++mt) {
      const int c = cs * 64 + ct * 16 + lhi * 4;
      const int q = q0 + mt * 16 + l16;
      unsigned short* dst = Ap + (((size_t)split * 4 + b) * CIN + c) * NPIX + q;
#pragma unroll
      for (int v = 0; v < 4; ++v) dst[(size_t)v * NPIX] = f2bf(acc[ct][mt][v]);
    }
}

// fused combine: out[b][c][q] = (A0 + A1) / sum_i Lp[i][b][q]
// vectorized partial sum: 16 f32x4 loads (16B-aligned, L2-resident) per thread
__global__ void combine(const unsigned short* __restrict__ Ap, const float* __restrict__ Lp,
                        float* __restrict__ out) {
  const size_t base = ((size_t)blockIdx.x * 256 + threadIdx.x) * 8;
  const int b = (int)(base / ((size_t)CIN * NPIX));
  const int q = (int)(base % NPIX);
  const u32x4 a0 = *(const u32x4*)(Ap + base);
  const u32x4 a1 = *(const u32x4*)(Ap + (size_t)4 * CIN * NPIX + base);
  const size_t lbase = (size_t)b * NPIX + q;      // q % 8 == 0 -> 16B-aligned
  f32x4 s0 = {0.f, 0.f, 0.f, 0.f}, s1 = {0.f, 0.f, 0.f, 0.f};
#pragma unroll
  for (int i = 0; i < 8; ++i) {
    const f32x4 u0 = *(const f32x4*)&Lp[(size_t)i * (4 * NPIX) + lbase];
    const f32x4 u1 = *(const f32x4*)&Lp[(size_t)i * (4 * NPIX) + lbase + 4];
    s0 += u0; s1 += u1;
  }
  float lv[8];
#pragma unroll
  for (int j = 0; j < 4; ++j) { lv[j] = 1.f / s0[j]; lv[4 + j] = 1.f / s1[j]; }
  float r[8];
#pragma unroll
  for (int i = 0; i < 4; ++i) {
    const float x0 = __builtin_bit_cast(float, (a0[i] & 0xFFFFu) << 16) +
                     __builtin_bit_cast(float, (a1[i] & 0xFFFFu) << 16);
    const float x1 = __builtin_bit_cast(float, (a0[i] & 0xFFFF0000u)) +
                     __builtin_bit_cast(float, (a1[i] & 0xFFFF0000u));
    r[2 * i] = x0 * lv[2 * i];
    r[2 * i + 1] = x1 * lv[2 * i + 1];
  }
  *(f32x4*)&out[base] = *(f32x4*)&r[0];
  *(f32x4*)&out[base + 4] = *(f32x4*)&r[4];
}

// ---------------- fallback flash attention (r2-proven; ws too small) ----------------
#define BN 32
__launch_bounds__(512, 2)
__global__ void attn_kernel(const unsigned short* __restrict__ F,
                            const unsigned short* __restrict__ G,
                            const unsigned short* __restrict__ H,
                            float* __restrict__ out) {
  __shared__ unsigned short Klds[32 * 40];
  __shared__ unsigned short Vlds[256 * 40];
  __shared__ unsigned short Plds[8][32 * 40];

  const int bid = blockIdx.x;
  const int b = bid >> 6;
  const int t = threadIdx.x;
  const int lane = t & 63;
  const int w = t >> 6;
  const int l16 = lane & 15;
  const int lhi = lane >> 4;
  const int m0 = ((bid & 63) << 6) + ((w >> 2) << 5);
  const int c0 = (w & 3) << 6;

  const f32x4 fzero = {0.f, 0.f, 0.f, 0.f};

  bf16x8 qf[2];
#pragma unroll
  for (int mt = 0; mt < 2; ++mt)
    qf[mt] = *(const bf16x8*)(G + ((size_t)b * NPIX + m0 + mt * 16 + l16) * DQK + lhi * 8);

  f32x4 acc[4][2];
#pragma unroll
  for (int ct = 0; ct < 4; ++ct)
#pragma unroll
    for (int mt = 0; mt < 2; ++mt) acc[ct][mt] = fzero;
  float Mr[2] = {-INFINITY, -INFINITY};
  float Lr[2] = {0.f, 0.f};

  const unsigned short* Fb = F + (size_t)b * NPIX * DQK;
  const unsigned short* Hb = H + (size_t)b * CIN * NPIX;
  unsigned short* Pw = &Plds[w][0];

  for (int n0 = 0; n0 < NPIX; n0 += BN) {
    __syncthreads();
    if (t < 128) {
      const int nr = t >> 2, sl = t & 3;
      *(u32x4*)&Klds[nr * 40 + sl * 8] = *(const u32x4*)(Fb + (size_t)(n0 + nr) * DQK + sl * 8);
    }
#pragma unroll
    for (int i = 0; i < 2; ++i) {
      const int q = t + i * 512;
      const int cr = q >> 2, sl = q & 3;
      *(u32x4*)&Vlds[cr * 40 + sl * 8] = *(const u32x4*)(Hb + (size_t)cr * NPIX + n0 + sl * 8);
    }
    __syncthreads();

    bf16x8 kf[2];
#pragma unroll
    for (int nts = 0; nts < 2; ++nts)
      kf[nts] = *(const bf16x8*)&Klds[(nts * 16 + l16) * 40 + lhi * 8];
    f32x4 s[2][2];
#pragma unroll
    for (int mt = 0; mt < 2; ++mt)
#pragma unroll
      for (int nts = 0; nts < 2; ++nts)
        s[mt][nts] = __builtin_amdgcn_mfma_f32_16x16x32_bf16(kf[nts], qf[mt], fzero, 0, 0, 0);

#pragma unroll
    for (int mt = 0; mt < 2; ++mt) {
      float tmax = s[mt][0][0];
#pragma unroll
      for (int v = 1; v < 4; ++v) tmax = fmaxf(tmax, s[mt][0][v]);
#pragma unroll
      for (int v = 0; v < 4; ++v) tmax = fmaxf(tmax, s[mt][1][v]);
      tmax = fmaxf(tmax, __shfl_xor(tmax, 16, 64));
      tmax = fmaxf(tmax, __shfl_xor(tmax, 32, 64));
      const float newM = fmaxf(Mr[mt], tmax);
      const float rescale = __expf(Mr[mt] - newM);
      Mr[mt] = newM;
      float p[2][4];
      float psum = 0.f;
#pragma unroll
      for (int nts = 0; nts < 2; ++nts)
#pragma unroll
        for (int v = 0; v < 4; ++v) {
          p[nts][v] = __expf(s[mt][nts][v] - newM);
          psum += p[nts][v];
        }
      psum += __shfl_xor(psum, 16, 64);
      psum += __shfl_xor(psum, 32, 64);
      Lr[mt] = Lr[mt] * rescale + psum;
#pragma unroll
      for (int ct = 0; ct < 4; ++ct) acc[ct][mt] *= rescale;
#pragma unroll
      for (int nts = 0; nts < 2; ++nts) {
        uint2 pkv;
        pkv.x = (unsigned)f2bf(p[nts][0]) | ((unsigned)f2bf(p[nts][1]) << 16);
        pkv.y = (unsigned)f2bf(p[nts][2]) | ((unsigned)f2bf(p[nts][3]) << 16);
        *(uint2*)&Pw[(mt * 16 + l16) * 40 + nts * 16 + lhi * 4] = pkv;
      }
    }
    asm volatile("" ::: "memory");

    bf16x8 pf[2];
#pragma unroll
    for (int mt = 0; mt < 2; ++mt)
      pf[mt] = *(const bf16x8*)&Pw[(mt * 16 + l16) * 40 + lhi * 8];
#pragma unroll
    for (int ct = 0; ct < 4; ++ct) {
      const bf16x8 vf = *(const bf16x8*)&Vlds[(c0 + ct * 16 + l16) * 40 + lhi * 8];
#pragma unroll
      for (int mt = 0; mt < 2; ++mt)
        acc[ct][mt] = __builtin_amdgcn_mfma_f32_16x16x32_bf16(vf, pf[mt], acc[ct][mt], 0, 0, 0);
    }
  }

#pragma unroll
  for (int mt = 0; mt < 2; ++mt) {
    const float invL = 1.f / Lr[mt];
    const int m = m0 + mt * 16 + l16;
#pragma unroll
    for (int ct = 0; ct < 4; ++ct)
#pragma unroll
      for (int v = 0; v < 4; ++v) {
        const int c = c0 + ct * 16 + lhi * 4 + v;
        out[((size_t)b * CIN + c) * NPIX + m] = acc[ct][mt][v] * invL;
      }
  }
}

extern "C" void kernel_launch(void* const* d_in, const int* in_sizes, int n_in,
                              void* d_out, int out_size, void* d_ws, size_t ws_size,
                              hipStream_t stream) {
  (void)in_sizes; (void)n_in; (void)out_size;
  const float* x  = (const float*)d_in[0];
  const float* Wf = (const float*)d_in[1];
  const float* bf = (const float*)d_in[2];
  const float* Wg = (const float*)d_in[3];
  const float* bg = (const float*)d_in[4];
  const float* Wh = (const float*)d_in[5];
  const float* bh = (const float*)d_in[6];
  float* out = (float*)d_out;

  unsigned short* Fw = (unsigned short*)d_ws;
  unsigned short* Gw = Fw + (size_t)BATCH * NPIX * DQK;
  unsigned short* Hw = Gw + (size_t)BATCH * NPIX * DQK;
  unsigned short* Wb = Hw + (size_t)BATCH * CIN * NPIX;
  float* bcat = (float*)(Wb + (size_t)MTOT * CIN);
  unsigned short* Apart = (unsigned short*)(bcat + MTOT);
  float* Lpart = (float*)(Apart + (size_t)2 * BATCH * CIN * NPIX);
  const size_t NEED = (size_t)((char*)(Lpart + (size_t)8 * BATCH * NPIX) - (char*)d_ws);

  hipLaunchKernelGGL(wcvt, dim3(MTOT), dim3(256), 0, stream, Wh, Wf, Wg, bh, bf, bg, Wb, bcat);
  hipLaunchKernelGGL(proj_all, dim3(BATCH * 64), dim3(512), 0, stream, x, Wb, bcat, Fw, Gw, Hw);

  if (ws_size >= NEED) {
    hipLaunchKernelGGL(attn_split, dim3(BATCH * 32 * 2), dim3(1024), 0, stream, Fw, Gw, Hw, Apart, Lpart);
    hipLaunchKernelGGL(combine, dim3((size_t)BATCH * CIN * NPIX / 8 / 256), dim3(256), 0, stream, Apart, Lpart, out);
  } else {
    hipLaunchKernelGGL(attn_kernel, dim3(BATCH * 64), dim3(512), 0, stream, Fw, Gw, Hw, out);
  }
}

// Round 22
// 81.820 us; speedup vs baseline: 1.2129x; 1.0149x over previous
//
#include <hip/hip_runtime.h>
#include <hip/hip_bf16.h>
#include <math.h>

#define BATCH 4
#define CIN   256
#define DQK   32
#define NPIX  4096
#define MTOT  320

typedef __attribute__((ext_vector_type(4))) float f32x4;
typedef __attribute__((ext_vector_type(8))) short bf16x8;
typedef __attribute__((ext_vector_type(4))) unsigned int u32x4;

__device__ __forceinline__ unsigned short f2bf(float f) {
  unsigned u = __builtin_bit_cast(unsigned, f);
  u += 0x7FFFu + ((u >> 16) & 1u);   // RNE
  return (unsigned short)(u >> 16);
}
__device__ __forceinline__ unsigned pk2(float a, float b) {
  return (unsigned)f2bf(a) | ((unsigned)f2bf(b) << 16);
}
__device__ __forceinline__ void wait_vm2_lgkm0() { asm volatile("s_waitcnt vmcnt(2) lgkmcnt(0)" ::: "memory"); }
__device__ __forceinline__ void wait_vm0_lgkm0() { asm volatile("s_waitcnt vmcnt(0) lgkmcnt(0)" ::: "memory"); }

#define GLD16(GP, LP) \
  __builtin_amdgcn_global_load_lds((const __attribute__((address_space(1))) void*)(GP), \
                                   (__attribute__((address_space(3))) void*)(LP), 16, 0, 0)

// ---------------- W convert ----------------
__global__ void wcvt(const float* __restrict__ Wh, const float* __restrict__ Wf,
                     const float* __restrict__ Wg,
                     const float* __restrict__ bh, const float* __restrict__ bf,
                     const float* __restrict__ bg,
                     unsigned short* __restrict__ Wb, float* __restrict__ bcat) {
  const int r = blockIdx.x;
  const int c = threadIdx.x;
  const float* src = (r < 256) ? &Wh[r * CIN] : (r < 288) ? &Wf[(r - 256) * CIN] : &Wg[(r - 288) * CIN];
  Wb[r * CIN + c] = f2bf(src[c]);
  if (c == 0)
    bcat[r] = (r < 256) ? bh[r] : (r < 288) ? bf[r - 256] : bg[r - 288];
}

// ---------------- fused projection GEMM (r2-proven) ----------------
#define XPAD 4
__launch_bounds__(512, 1)
__global__ void proj_all(const float* __restrict__ x, const unsigned short* __restrict__ Wb,
                         const float* __restrict__ bcat,
                         unsigned short* __restrict__ F, unsigned short* __restrict__ G,
                         unsigned short* __restrict__ H) {
  __shared__ unsigned short Xs[64 * (CIN + XPAD)];

  const int bid = blockIdx.x;
  const int b = bid >> 6;
  const int n0 = (bid & 63) << 6;
  const int t = threadIdx.x;
  const int lane = t & 63;
  const int w = t >> 6;

  const float* __restrict__ xb = x + (size_t)b * CIN * NPIX + n0;
#pragma unroll
  for (int p = 0; p < 16; ++p) {
    const int k = p * 16 + w * 2;
    const float a0 = xb[(size_t)k * NPIX + lane];
    const float a1 = xb[(size_t)(k + 1) * NPIX + lane];
    const unsigned pk = (unsigned)f2bf(a0) | ((unsigned)f2bf(a1) << 16);
    *(unsigned*)((char*)Xs + lane * (CIN + XPAD) * 2 + k * 2) = pk;
  }
  __syncthreads();

  const int l16 = lane & 15, lhi = lane >> 4;
  const int wm = w >> 1;
  const int wn = w & 1;

  const f32x4 fzero = {0.f, 0.f, 0.f, 0.f};
  f32x4 acc[5][2];
#pragma unroll
  for (int i = 0; i < 5; ++i)
#pragma unroll
    for (int j = 0; j < 2; ++j) acc[i][j] = fzero;

#pragma unroll
  for (int ks = 0; ks < 8; ++ks) {
    bf16x8 bx[2];
#pragma unroll
    for (int j = 0; j < 2; ++j)
      bx[j] = *(const bf16x8*)&Xs[(wn * 32 + j * 16 + l16) * (CIN + XPAD) + ks * 32 + lhi * 8];
#pragma unroll
    for (int i = 0; i < 5; ++i) {
      const bf16x8 aw = *(const bf16x8*)(Wb + (size_t)(wm * 80 + i * 16 + l16) * CIN + ks * 32 + lhi * 8);
#pragma unroll
      for (int j = 0; j < 2; ++j)
        acc[i][j] = __builtin_amdgcn_mfma_f32_16x16x32_bf16(aw, bx[j], acc[i][j], 0, 0, 0);
    }
  }

#pragma unroll
  for (int i = 0; i < 5; ++i) {
    const int MT = wm * 5 + i;
    const int m0 = MT * 16;
    const f32x4 bias = *(const f32x4*)&bcat[m0 + lhi * 4];
#pragma unroll
    for (int j = 0; j < 2; ++j) {
      const int n = n0 + wn * 32 + j * 16 + l16;
      f32x4 v = acc[i][j];
      v.x += bias.x; v.y += bias.y; v.z += bias.z; v.w += bias.w;
      if (MT < 16) {
        const int c0 = m0 + lhi * 4;
        unsigned short* dst = H + ((size_t)b * CIN + c0) * NPIX + n;
        dst[0 * NPIX] = f2bf(v.x);
        dst[1 * NPIX] = f2bf(v.y);
        dst[2 * NPIX] = f2bf(v.z);
        dst[3 * NPIX] = f2bf(v.w);
      } else {
        unsigned short* dst = (MT < 18) ? F : G;
        const int d0 = ((MT - 16) & 1) * 16 + lhi * 4;
        uint2 pk;
        pk.x = (unsigned)f2bf(v.x) | ((unsigned)f2bf(v.y) << 16);
        pk.y = (unsigned)f2bf(v.z) | ((unsigned)f2bf(v.w) << 16);
        *(uint2*)(dst + ((size_t)b * NPIX + n) * DQK + d0) = pk;
      }
    }
  }
}

// ---------------- key-split flash attention (r17-proven best) ----------------
// grid 256 (4b x 32qt x 2split, slab swizzle bid&7) x 16 waves (1024 thr). QT=128.
// Wave (mg 0..3, cs 0..3): QK = its 32 queries x 16-key slice (2 MFMA, no dup);
// PV = 64 channels x 32 queries (16 MFMA). K/V triple-buffered via
// global_load_lds (V: 2x16B/thread, K: waves 12-15, K issued FIRST).
// ONE {vmcnt(2)+lgkm0; barrier} per tile (ledger: wait keeps V(t+1)x2, retires
// V(t)+K(t+1)). P parity-double-buffered. M=0 softmax, __expf.
#define BNK  64
#define KEYS 2048
#define NTILE (KEYS / BNK)   // 32

__launch_bounds__(1024, 1)
__global__ void attn_split(const unsigned short* __restrict__ F,
                           const unsigned short* __restrict__ G,
                           const unsigned short* __restrict__ H,
                           unsigned short* __restrict__ Ap, float* __restrict__ Lp) {
  __shared__ unsigned short Kl[3][64][32];       // [buf][n][32d]  linear 12 KB
  __shared__ unsigned short Vl[3][256][64];      // [buf][c][64n]  linear 96 KB
  __shared__ unsigned short Pl[2][4][32][72];    // [parity][mg][q][64n+pad] 36.9 KB

  const int bid = blockIdx.x;
  const int slab = bid & 7;                      // (b,split) -> XCD under round-robin
  const int b = slab >> 1;
  const int split = slab & 1;
  const int qt = bid >> 3;                       // 0..31
  const int t = threadIdx.x;
  const int lane = t & 63, w = t >> 6;           // w 0..15
  const int l16 = lane & 15, lhi = lane >> 4;
  const int mg = w >> 2, cs = w & 3;

  const unsigned short* Fb = F + (size_t)b * NPIX * DQK;
  const unsigned short* Gb = G + (size_t)b * NPIX * DQK;
  const unsigned short* Hb = H + (size_t)b * CIN * NPIX;
  const int nb0 = split * KEYS;
  const int q0 = qt * 128 + mg * 32;             // wave's 32-query base

  const f32x4 fzero = {0.f, 0.f, 0.f, 0.f};

  // Q fragments (B-operand): col m = l16, k = lhi*8..+7
  bf16x8 qf[2];
#pragma unroll
  for (int mt = 0; mt < 2; ++mt)
    qf[mt] = *(const bf16x8*)(Gb + (size_t)(q0 + mt * 16 + l16) * DQK + lhi * 8);

  f32x4 acc[4][2];
#pragma unroll
  for (int ct = 0; ct < 4; ++ct)
#pragma unroll
    for (int mt = 0; mt < 2; ++mt) acc[ct][mt] = fzero;
  float Lacc[2] = {0.f, 0.f};

  // async staging sources (pre-swizzled; involution row&7 == lane>>3 preserved):
  const char* vsrc = (const char*)Hb + ((size_t)(8 * w + (lane >> 3)) * NPIX + nb0) * 2
                   + (((lane & 7) ^ (lane >> 3)) * 16);
  const int kw = (w >= 12) ? (w - 12) : 0;
  const char* ksrc = (const char*)Fb + ((size_t)(nb0 + 16 * kw + (lane >> 2)) * DQK) * 2
                   + (((lane & 3) ^ ((lane >> 2) & 3)) * 16);

// K issued FIRST so vmcnt(2) (keeping the 2 newer V loads) retires it on schedule
#define ISSUE(TT) do {                                                           \
    const int bu_ = (TT) % 3;                                                    \
    if (w >= 12)                                                                 \
      GLD16(ksrc + (size_t)(TT) * 64 * DQK * 2, &Kl[bu_][16 * kw][0]);           \
    _Pragma("unroll")                                                            \
    for (int i_ = 0; i_ < 2; ++i_)                                               \
      GLD16(vsrc + (size_t)i_ * 128 * NPIX * 2 + (size_t)(TT) * 128,             \
            &Vl[bu_][i_ * 128 + 8 * w][0]);                                      \
  } while (0)

  // QK (2 MFMA) + softmax -> P slice to Pl[PAR][mg]
#define QKSM(BUF3, PAR) do {                                                     \
    const unsigned short* kb_ = &Kl[BUF3][0][0];                                 \
    const bf16x8 kf_ = *(const bf16x8*)(kb_ + (cs * 16 + l16) * 32 + ((lhi ^ (l16 & 3)) * 8)); \
    f32x4 s_[2];                                                                 \
    _Pragma("unroll")                                                            \
    for (int mt_ = 0; mt_ < 2; ++mt_)                                            \
      s_[mt_] = __builtin_amdgcn_mfma_f32_16x16x32_bf16(kf_, qf[mt_], fzero, 0, 0, 0); \
    _Pragma("unroll")                                                            \
    for (int mt_ = 0; mt_ < 2; ++mt_) {                                          \
      const float p0 = __expf(s_[mt_][0]), p1 = __expf(s_[mt_][1]);              \
      const float p2 = __expf(s_[mt_][2]), p3 = __expf(s_[mt_][3]);              \
      Lacc[mt_] += (p0 + p1) + (p2 + p3);                                        \
      uint2 pk_; pk_.x = pk2(p0, p1); pk_.y = pk2(p2, p3);                       \
      *(uint2*)&Pl[PAR][mg][mt_ * 16 + l16][cs * 16 + lhi * 4] = pk_;            \
    }                                                                            \
  } while (0)

#define PVACC(BUF3, PF) do {                                                     \
    const unsigned short* vb_ = &Vl[BUF3][0][0];                                 \
    __builtin_amdgcn_s_setprio(1);                                               \
    _Pragma("unroll")                                                            \
    for (int kk_ = 0; kk_ < 2; ++kk_)                                            \
      _Pragma("unroll")                                                          \
      for (int ct_ = 0; ct_ < 4; ++ct_) {                                        \
        const bf16x8 vf_ = *(const bf16x8*)(vb_ + (cs * 64 + ct_ * 16 + l16) * 64 \
                            + (((4 * kk_ + lhi) ^ (l16 & 7)) * 8));              \
        _Pragma("unroll")                                                        \
        for (int mt_ = 0; mt_ < 2; ++mt_)                                        \
          acc[ct_][mt_] = __builtin_amdgcn_mfma_f32_16x16x32_bf16(vf_, PF[mt_][kk_], acc[ct_][mt_], 0, 0, 0); \
      }                                                                          \
    __builtin_amdgcn_s_setprio(0);                                               \
  } while (0)

  // prologue: tiles 0,1 in flight; vmcnt(2) retires {K0,V0,K1}, keeps V1x2
  ISSUE(0); ISSUE(1);
  wait_vm2_lgkm0();
  __builtin_amdgcn_s_barrier();
  asm volatile("" ::: "memory");
  QKSM(0, 0);

  for (int tt = 0; tt < NTILE; ++tt) {
    const int par = tt & 1;
    // the ONLY barrier per tile
    if (tt == NTILE - 1) wait_vm0_lgkm0(); else wait_vm2_lgkm0();
    __builtin_amdgcn_s_barrier();
    asm volatile("" ::: "memory");
    // buffer (tt+2)%3 was last read at iter tt-1 -> free now
    if (tt + 2 < NTILE) ISSUE(tt + 2);
    // pf: P(tt) reads issue early; latency covered by QKSM(tt+1)
    bf16x8 pf[2][2];
#pragma unroll
    for (int mt = 0; mt < 2; ++mt)
#pragma unroll
      for (int kk = 0; kk < 2; ++kk)
        pf[mt][kk] = *(const bf16x8*)&Pl[par][mg][mt * 16 + l16][kk * 32 + lhi * 8];
    if (tt + 1 < NTILE) QKSM((tt + 1) % 3, par ^ 1);
    PVACC(tt % 3, pf);
  }
#undef ISSUE
#undef QKSM
#undef PVACC

  // epilogue: L partials + unnormalized A (bf16)
#pragma unroll
  for (int mt = 0; mt < 2; ++mt) {
    float L = Lacc[mt];
    L += __shfl_xor(L, 16, 64);
    L += __shfl_xor(L, 32, 64);
    if (lhi == 0)
      Lp[((size_t)split * 4 + cs) * (4 * NPIX) + (size_t)b * NPIX + q0 + mt * 16 + l16] = L;
  }
#pragma unroll
  for (int ct = 0; ct < 4; ++ct)
#pragma unroll
    for (int mt = 0; mt < 2; ++mt) {
      const int c = cs * 64 + ct * 16 + lhi * 4;
      const int q = q0 + mt * 16 + l16;
      unsigned short* dst = Ap + (((size_t)split * 4 + b) * CIN + c) * NPIX + q;
#pragma unroll
      for (int v = 0; v < 4; ++v) dst[(size_t)v * NPIX] = f2bf(acc[ct][mt][v]);
    }
}

// sum the 8 L partials -> 1/L
__global__ void combineL(const float* __restrict__ Lp, float* __restrict__ Linv) {
  const int idx = blockIdx.x * 256 + threadIdx.x;
  float s = 0.f;
#pragma unroll
  for (int i = 0; i < 8; ++i) s += Lp[(size_t)i * (4 * NPIX) + idx];
  Linv[idx] = 1.f / s;
}

// out[b][c][q] = (A0 + A1) * Linv[b][q]
__global__ void combine(const unsigned short* __restrict__ Ap, const float* __restrict__ Linv,
                        float* __restrict__ out) {
  const size_t base = ((size_t)blockIdx.x * 256 + threadIdx.x) * 8;
  const int b = (int)(base / ((size_t)CIN * NPIX));
  const int q = (int)(base % NPIX);
  const u32x4 a0 = *(const u32x4*)(Ap + base);
  const u32x4 a1 = *(const u32x4*)(Ap + (size_t)4 * CIN * NPIX + base);
  const float* lv = &Linv[(size_t)b * NPIX + q];
  float r[8];
#pragma unroll
  for (int i = 0; i < 4; ++i) {
    const float x0 = __builtin_bit_cast(float, (a0[i] & 0xFFFFu) << 16) +
                     __builtin_bit_cast(float, (a1[i] & 0xFFFFu) << 16);
    const float x1 = __builtin_bit_cast(float, (a0[i] & 0xFFFF0000u)) +
                     __builtin_bit_cast(float, (a1[i] & 0xFFFF0000u));
    r[2 * i] = x0 * lv[2 * i];
    r[2 * i + 1] = x1 * lv[2 * i + 1];
  }
  *(f32x4*)&out[base] = *(f32x4*)&r[0];
  *(f32x4*)&out[base + 4] = *(f32x4*)&r[4];
}

// ---------------- fallback flash attention (r2-proven; ws too small) ----------------
#define BN 32
__launch_bounds__(512, 2)
__global__ void attn_kernel(const unsigned short* __restrict__ F,
                            const unsigned short* __restrict__ G,
                            const unsigned short* __restrict__ H,
                            float* __restrict__ out) {
  __shared__ unsigned short Klds[32 * 40];
  __shared__ unsigned short Vlds[256 * 40];
  __shared__ unsigned short Plds[8][32 * 40];

  const int bid = blockIdx.x;
  const int b = bid >> 6;
  const int t = threadIdx.x;
  const int lane = t & 63;
  const int w = t >> 6;
  const int l16 = lane & 15;
  const int lhi = lane >> 4;
  const int m0 = ((bid & 63) << 6) + ((w >> 2) << 5);
  const int c0 = (w & 3) << 6;

  const f32x4 fzero = {0.f, 0.f, 0.f, 0.f};

  bf16x8 qf[2];
#pragma unroll
  for (int mt = 0; mt < 2; ++mt)
    qf[mt] = *(const bf16x8*)(G + ((size_t)b * NPIX + m0 + mt * 16 + l16) * DQK + lhi * 8);

  f32x4 acc[4][2];
#pragma unroll
  for (int ct = 0; ct < 4; ++ct)
#pragma unroll
    for (int mt = 0; mt < 2; ++mt) acc[ct][mt] = fzero;
  float Mr[2] = {-INFINITY, -INFINITY};
  float Lr[2] = {0.f, 0.f};

  const unsigned short* Fb = F + (size_t)b * NPIX * DQK;
  const unsigned short* Hb = H + (size_t)b * CIN * NPIX;
  unsigned short* Pw = &Plds[w][0];

  for (int n0 = 0; n0 < NPIX; n0 += BN) {
    __syncthreads();
    if (t < 128) {
      const int nr = t >> 2, sl = t & 3;
      *(u32x4*)&Klds[nr * 40 + sl * 8] = *(const u32x4*)(Fb + (size_t)(n0 + nr) * DQK + sl * 8);
    }
#pragma unroll
    for (int i = 0; i < 2; ++i) {
      const int q = t + i * 512;
      const int cr = q >> 2, sl = q & 3;
      *(u32x4*)&Vlds[cr * 40 + sl * 8] = *(const u32x4*)(Hb + (size_t)cr * NPIX + n0 + sl * 8);
    }
    __syncthreads();

    bf16x8 kf[2];
#pragma unroll
    for (int nts = 0; nts < 2; ++nts)
      kf[nts] = *(const bf16x8*)&Klds[(nts * 16 + l16) * 40 + lhi * 8];
    f32x4 s[2][2];
#pragma unroll
    for (int mt = 0; mt < 2; ++mt)
#pragma unroll
      for (int nts = 0; nts < 2; ++nts)
        s[mt][nts] = __builtin_amdgcn_mfma_f32_16x16x32_bf16(kf[nts], qf[mt], fzero, 0, 0, 0);

#pragma unroll
    for (int mt = 0; mt < 2; ++mt) {
      float tmax = s[mt][0][0];
#pragma unroll
      for (int v = 1; v < 4; ++v) tmax = fmaxf(tmax, s[mt][0][v]);
#pragma unroll
      for (int v = 0; v < 4; ++v) tmax = fmaxf(tmax, s[mt][1][v]);
      tmax = fmaxf(tmax, __shfl_xor(tmax, 16, 64));
      tmax = fmaxf(tmax, __shfl_xor(tmax, 32, 64));
      const float newM = fmaxf(Mr[mt], tmax);
      const float rescale = __expf(Mr[mt] - newM);
      Mr[mt] = newM;
      float p[2][4];
      float psum = 0.f;
#pragma unroll
      for (int nts = 0; nts < 2; ++nts)
#pragma unroll
        for (int v = 0; v < 4; ++v) {
          p[nts][v] = __expf(s[mt][nts][v] - newM);
          psum += p[nts][v];
        }
      psum += __shfl_xor(psum, 16, 64);
      psum += __shfl_xor(psum, 32, 64);
      Lr[mt] = Lr[mt] * rescale + psum;
#pragma unroll
      for (int ct = 0; ct < 4; ++ct) acc[ct][mt] *= rescale;
#pragma unroll
      for (int nts = 0; nts < 2; ++nts) {
        uint2 pkv;
        pkv.x = (unsigned)f2bf(p[nts][0]) | ((unsigned)f2bf(p[nts][1]) << 16);
        pkv.y = (unsigned)f2bf(p[nts][2]) | ((unsigned)f2bf(p[nts][3]) << 16);
        *(uint2*)&Pw[(mt * 16 + l16) * 40 + nts * 16 + lhi * 4] = pkv;
      }
    }
    asm volatile("" ::: "memory");

    bf16x8 pf[2];
#pragma unroll
    for (int mt = 0; mt < 2; ++mt)
      pf[mt] = *(const bf16x8*)&Pw[(mt * 16 + l16) * 40 + lhi * 8];
#pragma unroll
    for (int ct = 0; ct < 4; ++ct) {
      const bf16x8 vf = *(const bf16x8*)&Vlds[(c0 + ct * 16 + l16) * 40 + lhi * 8];
#pragma unroll
      for (int mt = 0; mt < 2; ++mt)
        acc[ct][mt] = __builtin_amdgcn_mfma_f32_16x16x32_bf16(vf, pf[mt], acc[ct][mt], 0, 0, 0);
    }
  }

#pragma unroll
  for (int mt = 0; mt < 2; ++mt) {
    const float invL = 1.f / Lr[mt];
    const int m = m0 + mt * 16 + l16;
#pragma unroll
    for (int ct = 0; ct < 4; ++ct)
#pragma unroll
      for (int v = 0; v < 4; ++v) {
        const int c = c0 + ct * 16 + lhi * 4 + v;
        out[((size_t)b * CIN + c) * NPIX + m] = acc[ct][mt][v] * invL;
      }
  }
}

extern "C" void kernel_launch(void* const* d_in, const int* in_sizes, int n_in,
                              void* d_out, int out_size, void* d_ws, size_t ws_size,
                              hipStream_t stream) {
  (void)in_sizes; (void)n_in; (void)out_size;
  const float* x  = (const float*)d_in[0];
  const float* Wf = (const float*)d_in[1];
  const float* bf = (const float*)d_in[2];
  const float* Wg = (const float*)d_in[3];
  const float* bg = (const float*)d_in[4];
  const float* Wh = (const float*)d_in[5];
  const float* bh = (const float*)d_in[6];
  float* out = (float*)d_out;

  unsigned short* Fw = (unsigned short*)d_ws;
  unsigned short* Gw = Fw + (size_t)BATCH * NPIX * DQK;
  unsigned short* Hw = Gw + (size_t)BATCH * NPIX * DQK;
  unsigned short* Wb = Hw + (size_t)BATCH * CIN * NPIX;
  float* bcat = (float*)(Wb + (size_t)MTOT * CIN);
  unsigned short* Apart = (unsigned short*)(bcat + MTOT);
  float* Lpart = (float*)(Apart + (size_t)2 * BATCH * CIN * NPIX);
  float* Linv  = Lpart + (size_t)8 * BATCH * NPIX;
  const size_t NEED = (size_t)((char*)(Linv + (size_t)BATCH * NPIX) - (char*)d_ws);

  hipLaunchKernelGGL(wcvt, dim3(MTOT), dim3(256), 0, stream, Wh, Wf, Wg, bh, bf, bg, Wb, bcat);
  hipLaunchKernelGGL(proj_all, dim3(BATCH * 64), dim3(512), 0, stream, x, Wb, bcat, Fw, Gw, Hw);

  if (ws_size >= NEED) {
    hipLaunchKernelGGL(attn_split, dim3(BATCH * 32 * 2), dim3(1024), 0, stream, Fw, Gw, Hw, Apart, Lpart);
    hipLaunchKernelGGL(combineL, dim3(BATCH * NPIX / 256), dim3(256), 0, stream, Lpart, Linv);
    hipLaunchKernelGGL(combine, dim3((size_t)BATCH * CIN * NPIX / 8 / 256), dim3(256), 0, stream, Apart, Linv, out);
  } else {
    hipLaunchKernelGGL(attn_kernel, dim3(BATCH * 64), dim3(512), 0, stream, Fw, Gw, Hw, out);
  }
}

// Round 23
// 80.617 us; speedup vs baseline: 1.2311x; 1.0149x over previous
//
#include <hip/hip_runtime.h>
#include <hip/hip_bf16.h>
#include <math.h>

#define BATCH 4
#define CIN   256
#define DQK   32
#define NPIX  4096
#define MTOT  320

typedef __attribute__((ext_vector_type(4))) float f32x4;
typedef __attribute__((ext_vector_type(8))) short bf16x8;
typedef __attribute__((ext_vector_type(4))) unsigned int u32x4;

__device__ __forceinline__ unsigned short f2bf(float f) {
  unsigned u = __builtin_bit_cast(unsigned, f);
  u += 0x7FFFu + ((u >> 16) & 1u);   // RNE
  return (unsigned short)(u >> 16);
}
__device__ __forceinline__ unsigned pk2(float a, float b) {
  return (unsigned)f2bf(a) | ((unsigned)f2bf(b) << 16);
}
__device__ __forceinline__ void wait_vm2_lgkm0() { asm volatile("s_waitcnt vmcnt(2) lgkmcnt(0)" ::: "memory"); }
__device__ __forceinline__ void wait_vm0_lgkm0() { asm volatile("s_waitcnt vmcnt(0) lgkmcnt(0)" ::: "memory"); }

#define GLD16(GP, LP) \
  __builtin_amdgcn_global_load_lds((const __attribute__((address_space(1))) void*)(GP), \
                                   (__attribute__((address_space(3))) void*)(LP), 16, 0, 0)

// ---------------- W convert ----------------
__global__ void wcvt(const float* __restrict__ Wh, const float* __restrict__ Wf,
                     const float* __restrict__ Wg,
                     const float* __restrict__ bh, const float* __restrict__ bf,
                     const float* __restrict__ bg,
                     unsigned short* __restrict__ Wb, float* __restrict__ bcat) {
  const int r = blockIdx.x;
  const int c = threadIdx.x;
  const float* src = (r < 256) ? &Wh[r * CIN] : (r < 288) ? &Wf[(r - 256) * CIN] : &Wg[(r - 288) * CIN];
  Wb[r * CIN + c] = f2bf(src[c]);
  if (c == 0)
    bcat[r] = (r < 256) ? bh[r] : (r < 288) ? bf[r - 256] : bg[r - 288];
}

// ---------------- fused projection GEMM (r2-proven) ----------------
#define XPAD 4
__launch_bounds__(512, 1)
__global__ void proj_all(const float* __restrict__ x, const unsigned short* __restrict__ Wb,
                         const float* __restrict__ bcat,
                         unsigned short* __restrict__ F, unsigned short* __restrict__ G,
                         unsigned short* __restrict__ H) {
  __shared__ unsigned short Xs[64 * (CIN + XPAD)];

  const int bid = blockIdx.x;
  const int b = bid >> 6;
  const int n0 = (bid & 63) << 6;
  const int t = threadIdx.x;
  const int lane = t & 63;
  const int w = t >> 6;

  const float* __restrict__ xb = x + (size_t)b * CIN * NPIX + n0;
#pragma unroll
  for (int p = 0; p < 16; ++p) {
    const int k = p * 16 + w * 2;
    const float a0 = xb[(size_t)k * NPIX + lane];
    const float a1 = xb[(size_t)(k + 1) * NPIX + lane];
    const unsigned pk = (unsigned)f2bf(a0) | ((unsigned)f2bf(a1) << 16);
    *(unsigned*)((char*)Xs + lane * (CIN + XPAD) * 2 + k * 2) = pk;
  }
  __syncthreads();

  const int l16 = lane & 15, lhi = lane >> 4;
  const int wm = w >> 1;
  const int wn = w & 1;

  const f32x4 fzero = {0.f, 0.f, 0.f, 0.f};
  f32x4 acc[5][2];
#pragma unroll
  for (int i = 0; i < 5; ++i)
#pragma unroll
    for (int j = 0; j < 2; ++j) acc[i][j] = fzero;

#pragma unroll
  for (int ks = 0; ks < 8; ++ks) {
    bf16x8 bx[2];
#pragma unroll
    for (int j = 0; j < 2; ++j)
      bx[j] = *(const bf16x8*)&Xs[(wn * 32 + j * 16 + l16) * (CIN + XPAD) + ks * 32 + lhi * 8];
#pragma unroll
    for (int i = 0; i < 5; ++i) {
      const bf16x8 aw = *(const bf16x8*)(Wb + (size_t)(wm * 80 + i * 16 + l16) * CIN + ks * 32 + lhi * 8);
#pragma unroll
      for (int j = 0; j < 2; ++j)
        acc[i][j] = __builtin_amdgcn_mfma_f32_16x16x32_bf16(aw, bx[j], acc[i][j], 0, 0, 0);
    }
  }

#pragma unroll
  for (int i = 0; i < 5; ++i) {
    const int MT = wm * 5 + i;
    const int m0 = MT * 16;
    const f32x4 bias = *(const f32x4*)&bcat[m0 + lhi * 4];
#pragma unroll
    for (int j = 0; j < 2; ++j) {
      const int n = n0 + wn * 32 + j * 16 + l16;
      f32x4 v = acc[i][j];
      v.x += bias.x; v.y += bias.y; v.z += bias.z; v.w += bias.w;
      if (MT < 16) {
        const int c0 = m0 + lhi * 4;
        unsigned short* dst = H + ((size_t)b * CIN + c0) * NPIX + n;
        dst[0 * NPIX] = f2bf(v.x);
        dst[1 * NPIX] = f2bf(v.y);
        dst[2 * NPIX] = f2bf(v.z);
        dst[3 * NPIX] = f2bf(v.w);
      } else {
        unsigned short* dst = (MT < 18) ? F : G;
        const int d0 = ((MT - 16) & 1) * 16 + lhi * 4;
        uint2 pk;
        pk.x = (unsigned)f2bf(v.x) | ((unsigned)f2bf(v.y) << 16);
        pk.y = (unsigned)f2bf(v.z) | ((unsigned)f2bf(v.w) << 16);
        *(uint2*)(dst + ((size_t)b * NPIX + n) * DQK + d0) = pk;
      }
    }
  }
}

// ---------------- key-split flash attention (r17 structure, NO setprio) ----------------
// grid 256 (4b x 32qt x 2split, slab swizzle bid&7) x 16 waves (1024 thr). QT=128.
// Wave (mg 0..3, cs 0..3): QK = its 32 queries x 16-key slice (2 MFMA, no dup);
// PV = 64 channels x 32 queries (16 MFMA). K/V triple-buffered via
// global_load_lds (V: 2x16B/thread, K: waves 12-15, K issued FIRST).
// ONE {vmcnt(2)+lgkm0; barrier} per tile. P parity-double-buffered. M=0, __expf.
// A/B vs r22: s_setprio pair around PV REMOVED (T5 null/negative on lockstep
// schedules per m190; inherited untested since r4).
#define BNK  64
#define KEYS 2048
#define NTILE (KEYS / BNK)   // 32

__launch_bounds__(1024, 1)
__global__ void attn_split(const unsigned short* __restrict__ F,
                           const unsigned short* __restrict__ G,
                           const unsigned short* __restrict__ H,
                           unsigned short* __restrict__ Ap, float* __restrict__ Lp) {
  __shared__ unsigned short Kl[3][64][32];       // [buf][n][32d]  linear 12 KB
  __shared__ unsigned short Vl[3][256][64];      // [buf][c][64n]  linear 96 KB
  __shared__ unsigned short Pl[2][4][32][72];    // [parity][mg][q][64n+pad] 36.9 KB

  const int bid = blockIdx.x;
  const int slab = bid & 7;                      // (b,split) -> XCD under round-robin
  const int b = slab >> 1;
  const int split = slab & 1;
  const int qt = bid >> 3;                       // 0..31
  const int t = threadIdx.x;
  const int lane = t & 63, w = t >> 6;           // w 0..15
  const int l16 = lane & 15, lhi = lane >> 4;
  const int mg = w >> 2, cs = w & 3;

  const unsigned short* Fb = F + (size_t)b * NPIX * DQK;
  const unsigned short* Gb = G + (size_t)b * NPIX * DQK;
  const unsigned short* Hb = H + (size_t)b * CIN * NPIX;
  const int nb0 = split * KEYS;
  const int q0 = qt * 128 + mg * 32;             // wave's 32-query base

  const f32x4 fzero = {0.f, 0.f, 0.f, 0.f};

  // Q fragments (B-operand): col m = l16, k = lhi*8..+7
  bf16x8 qf[2];
#pragma unroll
  for (int mt = 0; mt < 2; ++mt)
    qf[mt] = *(const bf16x8*)(Gb + (size_t)(q0 + mt * 16 + l16) * DQK + lhi * 8);

  f32x4 acc[4][2];
#pragma unroll
  for (int ct = 0; ct < 4; ++ct)
#pragma unroll
    for (int mt = 0; mt < 2; ++mt) acc[ct][mt] = fzero;
  float Lacc[2] = {0.f, 0.f};

  // async staging sources (pre-swizzled; involution row&7 == lane>>3 preserved):
  const char* vsrc = (const char*)Hb + ((size_t)(8 * w + (lane >> 3)) * NPIX + nb0) * 2
                   + (((lane & 7) ^ (lane >> 3)) * 16);
  const int kw = (w >= 12) ? (w - 12) : 0;
  const char* ksrc = (const char*)Fb + ((size_t)(nb0 + 16 * kw + (lane >> 2)) * DQK) * 2
                   + (((lane & 3) ^ ((lane >> 2) & 3)) * 16);

// K issued FIRST so vmcnt(2) (keeping the 2 newer V loads) retires it on schedule
#define ISSUE(TT) do {                                                           \
    const int bu_ = (TT) % 3;                                                    \
    if (w >= 12)                                                                 \
      GLD16(ksrc + (size_t)(TT) * 64 * DQK * 2, &Kl[bu_][16 * kw][0]);           \
    _Pragma("unroll")                                                            \
    for (int i_ = 0; i_ < 2; ++i_)                                               \
      GLD16(vsrc + (size_t)i_ * 128 * NPIX * 2 + (size_t)(TT) * 128,             \
            &Vl[bu_][i_ * 128 + 8 * w][0]);                                      \
  } while (0)

  // QK (2 MFMA) + softmax -> P slice to Pl[PAR][mg]
#define QKSM(BUF3, PAR) do {                                                     \
    const unsigned short* kb_ = &Kl[BUF3][0][0];                                 \
    const bf16x8 kf_ = *(const bf16x8*)(kb_ + (cs * 16 + l16) * 32 + ((lhi ^ (l16 & 3)) * 8)); \
    f32x4 s_[2];                                                                 \
    _Pragma("unroll")                                                            \
    for (int mt_ = 0; mt_ < 2; ++mt_)                                            \
      s_[mt_] = __builtin_amdgcn_mfma_f32_16x16x32_bf16(kf_, qf[mt_], fzero, 0, 0, 0); \
    _Pragma("unroll")                                                            \
    for (int mt_ = 0; mt_ < 2; ++mt_) {                                          \
      const float p0 = __expf(s_[mt_][0]), p1 = __expf(s_[mt_][1]);              \
      const float p2 = __expf(s_[mt_][2]), p3 = __expf(s_[mt_][3]);              \
      Lacc[mt_] += (p0 + p1) + (p2 + p3);                                        \
      uint2 pk_; pk_.x = pk2(p0, p1); pk_.y = pk2(p2, p3);                       \
      *(uint2*)&Pl[PAR][mg][mt_ * 16 + l16][cs * 16 + lhi * 4] = pk_;            \
    }                                                                            \
  } while (0)

#define PVACC(BUF3, PF) do {                                                     \
    const unsigned short* vb_ = &Vl[BUF3][0][0];                                 \
    _Pragma("unroll")                                                            \
    for (int kk_ = 0; kk_ < 2; ++kk_)                                            \
      _Pragma("unroll")                                                          \
      for (int ct_ = 0; ct_ < 4; ++ct_) {                                        \
        const bf16x8 vf_ = *(const bf16x8*)(vb_ + (cs * 64 + ct_ * 16 + l16) * 64 \
                            + (((4 * kk_ + lhi) ^ (l16 & 7)) * 8));              \
        _Pragma("unroll")                                                        \
        for (int mt_ = 0; mt_ < 2; ++mt_)                                        \
          acc[ct_][mt_] = __builtin_amdgcn_mfma_f32_16x16x32_bf16(vf_, PF[mt_][kk_], acc[ct_][mt_], 0, 0, 0); \
      }                                                                          \
  } while (0)

  // prologue: tiles 0,1 in flight; vmcnt(2) retires {K0,V0,K1}, keeps V1x2
  ISSUE(0); ISSUE(1);
  wait_vm2_lgkm0();
  __builtin_amdgcn_s_barrier();
  asm volatile("" ::: "memory");
  QKSM(0, 0);

  for (int tt = 0; tt < NTILE; ++tt) {
    const int par = tt & 1;
    // the ONLY barrier per tile
    if (tt == NTILE - 1) wait_vm0_lgkm0(); else wait_vm2_lgkm0();
    __builtin_amdgcn_s_barrier();
    asm volatile("" ::: "memory");
    // buffer (tt+2)%3 was last read at iter tt-1 -> free now
    if (tt + 2 < NTILE) ISSUE(tt + 2);
    // pf: P(tt) reads issue early; latency covered by QKSM(tt+1)
    bf16x8 pf[2][2];
#pragma unroll
    for (int mt = 0; mt < 2; ++mt)
#pragma unroll
      for (int kk = 0; kk < 2; ++kk)
        pf[mt][kk] = *(const bf16x8*)&Pl[par][mg][mt * 16 + l16][kk * 32 + lhi * 8];
    if (tt + 1 < NTILE) QKSM((tt + 1) % 3, par ^ 1);
    PVACC(tt % 3, pf);
  }
#undef ISSUE
#undef QKSM
#undef PVACC

  // epilogue: L partials + unnormalized A (bf16)
#pragma unroll
  for (int mt = 0; mt < 2; ++mt) {
    float L = Lacc[mt];
    L += __shfl_xor(L, 16, 64);
    L += __shfl_xor(L, 32, 64);
    if (lhi == 0)
      Lp[((size_t)split * 4 + cs) * (4 * NPIX) + (size_t)b * NPIX + q0 + mt * 16 + l16] = L;
  }
#pragma unroll
  for (int ct = 0; ct < 4; ++ct)
#pragma unroll
    for (int mt = 0; mt < 2; ++mt) {
      const int c = cs * 64 + ct * 16 + lhi * 4;
      const int q = q0 + mt * 16 + l16;
      unsigned short* dst = Ap + (((size_t)split * 4 + b) * CIN + c) * NPIX + q;
#pragma unroll
      for (int v = 0; v < 4; ++v) dst[(size_t)v * NPIX] = f2bf(acc[ct][mt][v]);
    }
}

// sum the 8 L partials -> 1/L
__global__ void combineL(const float* __restrict__ Lp, float* __restrict__ Linv) {
  const int idx = blockIdx.x * 256 + threadIdx.x;
  float s = 0.f;
#pragma unroll
  for (int i = 0; i < 8; ++i) s += Lp[(size_t)i * (4 * NPIX) + idx];
  Linv[idx] = 1.f / s;
}

// out[b][c][q] = (A0 + A1) * Linv[b][q]
__global__ void combine(const unsigned short* __restrict__ Ap, const float* __restrict__ Linv,
                        float* __restrict__ out) {
  const size_t base = ((size_t)blockIdx.x * 256 + threadIdx.x) * 8;
  const int b = (int)(base / ((size_t)CIN * NPIX));
  const int q = (int)(base % NPIX);
  const u32x4 a0 = *(const u32x4*)(Ap + base);
  const u32x4 a1 = *(const u32x4*)(Ap + (size_t)4 * CIN * NPIX + base);
  const float* lv = &Linv[(size_t)b * NPIX + q];
  float r[8];
#pragma unroll
  for (int i = 0; i < 4; ++i) {
    const float x0 = __builtin_bit_cast(float, (a0[i] & 0xFFFFu) << 16) +
                     __builtin_bit_cast(float, (a1[i] & 0xFFFFu) << 16);
    const float x1 = __builtin_bit_cast(float, (a0[i] & 0xFFFF0000u)) +
                     __builtin_bit_cast(float, (a1[i] & 0xFFFF0000u));
    r[2 * i] = x0 * lv[2 * i];
    r[2 * i + 1] = x1 * lv[2 * i + 1];
  }
  *(f32x4*)&out[base] = *(f32x4*)&r[0];
  *(f32x4*)&out[base + 4] = *(f32x4*)&r[4];
}

// ---------------- fallback flash attention (r2-proven; ws too small) ----------------
#define BN 32
__launch_bounds__(512, 2)
__global__ void attn_kernel(const unsigned short* __restrict__ F,
                            const unsigned short* __restrict__ G,
                            const unsigned short* __restrict__ H,
                            float* __restrict__ out) {
  __shared__ unsigned short Klds[32 * 40];
  __shared__ unsigned short Vlds[256 * 40];
  __shared__ unsigned short Plds[8][32 * 40];

  const int bid = blockIdx.x;
  const int b = bid >> 6;
  const int t = threadIdx.x;
  const int lane = t & 63;
  const int w = t >> 6;
  const int l16 = lane & 15;
  const int lhi = lane >> 4;
  const int m0 = ((bid & 63) << 6) + ((w >> 2) << 5);
  const int c0 = (w & 3) << 6;

  const f32x4 fzero = {0.f, 0.f, 0.f, 0.f};

  bf16x8 qf[2];
#pragma unroll
  for (int mt = 0; mt < 2; ++mt)
    qf[mt] = *(const bf16x8*)(G + ((size_t)b * NPIX + m0 + mt * 16 + l16) * DQK + lhi * 8);

  f32x4 acc[4][2];
#pragma unroll
  for (int ct = 0; ct < 4; ++ct)
#pragma unroll
    for (int mt = 0; mt < 2; ++mt) acc[ct][mt] = fzero;
  float Mr[2] = {-INFINITY, -INFINITY};
  float Lr[2] = {0.f, 0.f};

  const unsigned short* Fb = F + (size_t)b * NPIX * DQK;
  const unsigned short* Hb = H + (size_t)b * CIN * NPIX;
  unsigned short* Pw = &Plds[w][0];

  for (int n0 = 0; n0 < NPIX; n0 += BN) {
    __syncthreads();
    if (t < 128) {
      const int nr = t >> 2, sl = t & 3;
      *(u32x4*)&Klds[nr * 40 + sl * 8] = *(const u32x4*)(Fb + (size_t)(n0 + nr) * DQK + sl * 8);
    }
#pragma unroll
    for (int i = 0; i < 2; ++i) {
      const int q = t + i * 512;
      const int cr = q >> 2, sl = q & 3;
      *(u32x4*)&Vlds[cr * 40 + sl * 8] = *(const u32x4*)(Hb + (size_t)cr * NPIX + n0 + sl * 8);
    }
    __syncthreads();

    bf16x8 kf[2];
#pragma unroll
    for (int nts = 0; nts < 2; ++nts)
      kf[nts] = *(const bf16x8*)&Klds[(nts * 16 + l16) * 40 + lhi * 8];
    f32x4 s[2][2];
#pragma unroll
    for (int mt = 0; mt < 2; ++mt)
#pragma unroll
      for (int nts = 0; nts < 2; ++nts)
        s[mt][nts] = __builtin_amdgcn_mfma_f32_16x16x32_bf16(kf[nts], qf[mt], fzero, 0, 0, 0);

#pragma unroll
    for (int mt = 0; mt < 2; ++mt) {
      float tmax = s[mt][0][0];
#pragma unroll
      for (int v = 1; v < 4; ++v) tmax = fmaxf(tmax, s[mt][0][v]);
#pragma unroll
      for (int v = 0; v < 4; ++v) tmax = fmaxf(tmax, s[mt][1][v]);
      tmax = fmaxf(tmax, __shfl_xor(tmax, 16, 64));
      tmax = fmaxf(tmax, __shfl_xor(tmax, 32, 64));
      const float newM = fmaxf(Mr[mt], tmax);
      const float rescale = __expf(Mr[mt] - newM);
      Mr[mt] = newM;
      float p[2][4];
      float psum = 0.f;
#pragma unroll
      for (int nts = 0; nts < 2; ++nts)
#pragma unroll
        for (int v = 0; v < 4; ++v) {
          p[nts][v] = __expf(s[mt][nts][v] - newM);
          psum += p[nts][v];
        }
      psum += __shfl_xor(psum, 16, 64);
      psum += __shfl_xor(psum, 32, 64);
      Lr[mt] = Lr[mt] * rescale + psum;
#pragma unroll
      for (int ct = 0; ct < 4; ++ct) acc[ct][mt] *= rescale;
#pragma unroll
      for (int nts = 0; nts < 2; ++nts) {
        uint2 pkv;
        pkv.x = (unsigned)f2bf(p[nts][0]) | ((unsigned)f2bf(p[nts][1]) << 16);
        pkv.y = (unsigned)f2bf(p[nts][2]) | ((unsigned)f2bf(p[nts][3]) << 16);
        *(uint2*)&Pw[(mt * 16 + l16) * 40 + nts * 16 + lhi * 4] = pkv;
      }
    }
    asm volatile("" ::: "memory");

    bf16x8 pf[2];
#pragma unroll
    for (int mt = 0; mt < 2; ++mt)
      pf[mt] = *(const bf16x8*)&Pw[(mt * 16 + l16) * 40 + lhi * 8];
#pragma unroll
    for (int ct = 0; ct < 4; ++ct) {
      const bf16x8 vf = *(const bf16x8*)&Vlds[(c0 + ct * 16 + l16) * 40 + lhi * 8];
#pragma unroll
      for (int mt = 0; mt < 2; ++mt)
        acc[ct][mt] = __builtin_amdgcn_mfma_f32_16x16x32_bf16(vf, pf[mt], acc[ct][mt], 0, 0, 0);
    }
  }

#pragma unroll
  for (int mt = 0; mt < 2; ++mt) {
    const float invL = 1.f / Lr[mt];
    const int m = m0 + mt * 16 + l16;
#pragma unroll
    for (int ct = 0; ct < 4; ++ct)
#pragma unroll
      for (int v = 0; v < 4; ++v) {
        const int c = c0 + ct * 16 + lhi * 4 + v;
        out[((size_t)b * CIN + c) * NPIX + m] = acc[ct][mt][v] * invL;
      }
  }
}

extern "C" void kernel_launch(void* const* d_in, const int* in_sizes, int n_in,
                              void* d_out, int out_size, void* d_ws, size_t ws_size,
                              hipStream_t stream) {
  (void)in_sizes; (void)n_in; (void)out_size;
  const float* x  = (const float*)d_in[0];
  const float* Wf = (const float*)d_in[1];
  const float* bf = (const float*)d_in[2];
  const float* Wg = (const float*)d_in[3];
  const float* bg = (const float*)d_in[4];
  const float* Wh = (const float*)d_in[5];
  const float* bh = (const float*)d_in[6];
  float* out = (float*)d_out;

  unsigned short* Fw = (unsigned short*)d_ws;
  unsigned short* Gw = Fw + (size_t)BATCH * NPIX * DQK;
  unsigned short* Hw = Gw + (size_t)BATCH * NPIX * DQK;
  unsigned short* Wb = Hw + (size_t)BATCH * CIN * NPIX;
  float* bcat = (float*)(Wb + (size_t)MTOT * CIN);
  unsigned short* Apart = (unsigned short*)(bcat + MTOT);
  float* Lpart = (float*)(Apart + (size_t)2 * BATCH * CIN * NPIX);
  float* Linv  = Lpart + (size_t)8 * BATCH * NPIX;
  const size_t NEED = (size_t)((char*)(Linv + (size_t)BATCH * NPIX) - (char*)d_ws);

  hipLaunchKernelGGL(wcvt, dim3(MTOT), dim3(256), 0, stream, Wh, Wf, Wg, bh, bf, bg, Wb, bcat);
  hipLaunchKernelGGL(proj_all, dim3(BATCH * 64), dim3(512), 0, stream, x, Wb, bcat, Fw, Gw, Hw);

  if (ws_size >= NEED) {
    hipLaunchKernelGGL(attn_split, dim3(BATCH * 32 * 2), dim3(1024), 0, stream, Fw, Gw, Hw, Apart, Lpart);
    hipLaunchKernelGGL(combineL, dim3(BATCH * NPIX / 256), dim3(256), 0, stream, Lpart, Linv);
    hipLaunchKernelGGL(combine, dim3((size_t)BATCH * CIN * NPIX / 8 / 256), dim3(256), 0, stream, Apart, Linv, out);
  } else {
    hipLaunchKernelGGL(attn_kernel, dim3(BATCH * 64), dim3(512), 0, stream, Fw, Gw, Hw, out);
  }
}